// Round 9
// baseline (177.696 us; speedup 1.0000x reference)
//
#include <hip/hip_runtime.h>
#include <hip/hip_bf16.h>

// Sizes fixed by the reference
#define V 50000
#define D 256
#define B 256
#define C 10
#define TWO_D 512
#define VBLK 32
#define NGI 521                        // tile-groups; 521*3 = 1563 tiles exactly
#define TPB 3                          // tiles per wave
#define NBLK_OUT NGI
#define MPAD 4096                      // 256 b * 16 (c padded 10 -> 16)

typedef __bf16 bf16x8 __attribute__((ext_vector_type(8)));
typedef float f32x4 __attribute__((ext_vector_type(4)));
typedef unsigned short ushort_t;
typedef unsigned int uint_t;

__device__ inline ushort_t f2bf(float f) {
    uint_t u = __builtin_bit_cast(uint_t, f);
    uint_t r = (u + 0x7FFFu + ((u >> 16) & 1u)) >> 16;
    return (ushort_t)r;
}

__device__ inline float softplus_f(float x) {
    return (x > 0.f) ? (x + log1pf(__expf(-x))) : log1pf(__expf(x));
}

__device__ inline float wave_reduce(float v) {
    #pragma unroll
    for (int m = 1; m < 64; m <<= 1) v += __shfl_xor(v, m);
    return v;
}

// counted vmcnt wait
#define SWAIT(N) do { \
    asm volatile("s_waitcnt vmcnt(" #N ")" ::: "memory"); \
    __builtin_amdgcn_sched_barrier(0); \
} while (0)

// ---------------------------------------------------------------------------
// K0 (unchanged, proven)
// ---------------------------------------------------------------------------
__global__ __launch_bounds__(256) void k0_gather(
    const int* __restrict__ center_id, const int* __restrict__ context_ids,
    const float* __restrict__ embeddings, ushort_t* __restrict__ xbf)
{
    const int idx = blockIdx.x * 256 + threadIdx.x;
    const int m = idx >> 7;
    const int q = idx & 127;
    const int k = q * 4;
    const int b = m >> 4, c = m & 15;
    ushort4 o;
    if (k < D) {
        const float4 v = *(const float4*)(embeddings + center_id[b] * D + k);
        o.x = f2bf(v.x); o.y = f2bf(v.y); o.z = f2bf(v.z); o.w = f2bf(v.w);
    } else if (c < C) {
        const float4 v = *(const float4*)(embeddings + context_ids[b * C + c] * D + (k - D));
        o.x = f2bf(v.x); o.y = f2bf(v.y); o.z = f2bf(v.z); o.w = f2bf(v.w);
    } else {
        o.x = 0; o.y = 0; o.z = 0; o.w = 0;
    }
    *(ushort4*)(xbf + idx * 4) = o;
}

// ---------------------------------------------------------------------------
// K_enc (unchanged, proven)
// ---------------------------------------------------------------------------
__global__ __launch_bounds__(256) void k_enc(
    const float* __restrict__ enc_W, const float* __restrict__ enc_b,
    const ushort_t* __restrict__ xbf, ushort_t* __restrict__ h_bf)
{
    __shared__ __align__(16) ushort_t wt[2][64 * 40];
    const int tid = threadIdx.x;
    const int mblk = blockIdx.x & 63;
    const int nblk = blockIdx.x >> 6;
    const int n0 = nblk * 64;
    const int wid = tid >> 6, lane = tid & 63;
    const int l15 = lane & 15, g = lane >> 4;

    const int r0 = tid >> 3, kq = tid & 7, r1 = r0 + 32;
    const float* src0 = enc_W + (n0 + r0) * TWO_D + kq * 4;
    const float* src1 = enc_W + (n0 + r1) * TWO_D + kq * 4;
    const int dst0 = r0 * 40 + kq * 4;
    const int dst1 = r1 * 40 + kq * 4;

    {
        const float4 na = *(const float4*)(src0);
        const float4 nb = *(const float4*)(src1);
        ushort4 pa, pb;
        pa.x = f2bf(na.x); pa.y = f2bf(na.y); pa.z = f2bf(na.z); pa.w = f2bf(na.w);
        pb.x = f2bf(nb.x); pb.y = f2bf(nb.y); pb.z = f2bf(nb.z); pb.w = f2bf(nb.w);
        *(ushort4*)(&wt[0][dst0]) = pa;
        *(ushort4*)(&wt[0][dst1]) = pb;
    }
    __syncthreads();

    const int rowA = mblk * 64 + wid * 16 + l15;
    f32x4 acc[4] = {};
    #pragma unroll 1
    for (int kk = 0; kk < 16; ++kk) {
        const int cur = kk & 1, nxt = cur ^ 1;
        float4 na, nb;
        if (kk < 15) {
            na = *(const float4*)(src0 + (kk + 1) * 32);
            nb = *(const float4*)(src1 + (kk + 1) * 32);
        }
        const bf16x8 A = *(const bf16x8*)(xbf + rowA * TWO_D + kk * 32 + g * 8);
        bf16x8 Bf[4];
        #pragma unroll
        for (int vt = 0; vt < 4; ++vt)
            Bf[vt] = *(const bf16x8*)(&wt[cur][(vt * 16 + l15) * 40 + g * 8]);
        #pragma unroll
        for (int vt = 0; vt < 4; ++vt)
            acc[vt] = __builtin_amdgcn_mfma_f32_16x16x32_bf16(A, Bf[vt], acc[vt], 0, 0, 0);
        if (kk < 15) {
            ushort4 pa, pb;
            pa.x = f2bf(na.x); pa.y = f2bf(na.y); pa.z = f2bf(na.z); pa.w = f2bf(na.w);
            pb.x = f2bf(nb.x); pb.y = f2bf(nb.y); pb.z = f2bf(nb.z); pb.w = f2bf(nb.w);
            *(ushort4*)(&wt[nxt][dst0]) = pa;
            *(ushort4*)(&wt[nxt][dst1]) = pb;
        }
        __syncthreads();
    }

    const int b = mblk * 4 + wid;
    #pragma unroll
    for (int vt = 0; vt < 4; ++vt) {
        const int j = n0 + vt * 16 + l15;
        const float bias = enc_b[j];
        float s = 0.f;
        #pragma unroll
        for (int r = 0; r < 4; ++r) {
            const int c = g * 4 + r;
            const float vv = acc[vt][r] + bias;
            s += (c < C) ? fmaxf(vv, 0.f) : 0.f;
        }
        s += __shfl_xor(s, 16);
        s += __shfl_xor(s, 32);
        if (g == 0) h_bf[b * TWO_D + j] = f2bf(s);
    }
}

// ---------------------------------------------------------------------------
// K_heads (unchanged, proven)
// ---------------------------------------------------------------------------
__global__ __launch_bounds__(256) void k_heads(
    const float* __restrict__ mean_W, const float* __restrict__ mean_b,
    const float* __restrict__ var_W, const float* __restrict__ var_b,
    const ushort_t* __restrict__ h_bf, float* __restrict__ mv)
{
    __shared__ __align__(16) ushort_t wt[2][64 * 40];
    const int tid = threadIdx.x;
    const int mblk = blockIdx.x & 3;
    const int nblk = blockIdx.x >> 2;
    const int n0 = nblk * 64;
    const float* Wsrc = (nblk < 4) ? mean_W : var_W;
    const float* bsrc = (nblk < 4) ? mean_b : var_b;
    const int nloc = (nblk & 3) * 64;
    const int wid = tid >> 6, lane = tid & 63;
    const int l15 = lane & 15, g = lane >> 4;

    const int r0 = tid >> 3, kq = tid & 7, r1 = r0 + 32;
    const float* src0 = Wsrc + (nloc + r0) * TWO_D + kq * 4;
    const float* src1 = Wsrc + (nloc + r1) * TWO_D + kq * 4;
    const int dst0 = r0 * 40 + kq * 4;
    const int dst1 = r1 * 40 + kq * 4;

    {
        const float4 na = *(const float4*)(src0);
        const float4 nb = *(const float4*)(src1);
        ushort4 pa, pb;
        pa.x = f2bf(na.x); pa.y = f2bf(na.y); pa.z = f2bf(na.z); pa.w = f2bf(na.w);
        pb.x = f2bf(nb.x); pb.y = f2bf(nb.y); pb.z = f2bf(nb.z); pb.w = f2bf(nb.w);
        *(ushort4*)(&wt[0][dst0]) = pa;
        *(ushort4*)(&wt[0][dst1]) = pb;
    }
    __syncthreads();

    const int rowA = mblk * 64 + wid * 16 + l15;
    f32x4 acc[4] = {};
    #pragma unroll 1
    for (int kk = 0; kk < 16; ++kk) {
        const int cur = kk & 1, nxt = cur ^ 1;
        float4 na, nb;
        if (kk < 15) {
            na = *(const float4*)(src0 + (kk + 1) * 32);
            nb = *(const float4*)(src1 + (kk + 1) * 32);
        }
        const bf16x8 A = *(const bf16x8*)(h_bf + rowA * TWO_D + kk * 32 + g * 8);
        bf16x8 Bf[4];
        #pragma unroll
        for (int vt = 0; vt < 4; ++vt)
            Bf[vt] = *(const bf16x8*)(&wt[cur][(vt * 16 + l15) * 40 + g * 8]);
        #pragma unroll
        for (int vt = 0; vt < 4; ++vt)
            acc[vt] = __builtin_amdgcn_mfma_f32_16x16x32_bf16(A, Bf[vt], acc[vt], 0, 0, 0);
        if (kk < 15) {
            ushort4 pa, pb;
            pa.x = f2bf(na.x); pa.y = f2bf(na.y); pa.z = f2bf(na.z); pa.w = f2bf(na.w);
            pb.x = f2bf(nb.x); pb.y = f2bf(nb.y); pb.z = f2bf(nb.z); pb.w = f2bf(nb.w);
            *(ushort4*)(&wt[nxt][dst0]) = pa;
            *(ushort4*)(&wt[nxt][dst1]) = pb;
        }
        __syncthreads();
    }

    const int rowBase = mblk * 64 + wid * 16;
    #pragma unroll
    for (int vt = 0; vt < 4; ++vt) {
        const int col = n0 + vt * 16 + l15;
        const float bias = bsrc[nloc + vt * 16 + l15];
        #pragma unroll
        for (int r = 0; r < 4; ++r) {
            const int row = rowBase + g * 4 + r;
            mv[row * TWO_D + col] = acc[vt][r] + bias;
        }
    }
}

// ---------------------------------------------------------------------------
// K_z (unchanged from round 8 — packed zp write, proven)
// ---------------------------------------------------------------------------
__global__ __launch_bounds__(256) void k_z(
    const int* __restrict__ center_id, const int* __restrict__ context_ids,
    const float* __restrict__ prior_means_w, const float* __restrict__ prior_vars_w,
    const float* __restrict__ vocab_W, const float* __restrict__ vocab_b,
    const float* __restrict__ epsilon, const float* __restrict__ mv,
    ushort_t* __restrict__ zp, float* __restrict__ base)
{
    __shared__ float red[8];
    __shared__ int cids[C];
    const int b = blockIdx.x, tid = threadIdx.x;
    const int cid = center_id[b];
    if (tid < C) cids[tid] = context_ids[b * C + tid];
    __syncthreads();

    const int i = tid;
    const float mean = mv[b * TWO_D + i];
    const float a    = mv[b * TWO_D + D + i];
    const float var  = softplus_f(a);
    const float z    = mean + __expf(0.5f * var) * epsilon[i];

    {
        const int mt  = b >> 4;
        const int kkz = i >> 5;
        const int lz  = ((i >> 3) & 3) * 16 + (b & 15);
        zp[(mt * 8 + kkz) * 512 + lz * 8 + (i & 7)] = f2bf(z);
    }

    const float pm = prior_means_w[cid * D + i];
    const float pv = softplus_f(prior_vars_w[cid * D + i]);
    const float dm = pm - mean;
    float klt = var / pv + dm * dm / pv - 1.f + __logf(pv) - __logf(var);

    float wsum = 0.f;
    #pragma unroll
    for (int c = 0; c < C; ++c) wsum += vocab_W[cids[c] * D + i];
    float p = z * wsum;

    klt = wave_reduce(klt);
    p = wave_reduce(p);
    const int wid = tid >> 6, lane = tid & 63;
    if (lane == 0) { red[wid] = klt; red[4 + wid] = p; }
    __syncthreads();
    if (tid == 0) {
        const float kl = 0.5f * (red[0] + red[1] + red[2] + red[3]);
        float cs = red[4] + red[5] + red[6] + red[7];
        #pragma unroll
        for (int c = 0; c < C; ++c) cs += vocab_b[cids[c]];
        base[b] = cs - kl;
    }
}

// === shared macros for k3 family ===========================================
#define K3_PRELUDE \
    const int lane = threadIdx.x; \
    const int l15 = lane & 15, g = lane >> 4; \
    const int bid = blockIdx.x; \
    const int gi = bid >> 2, rg = bid & 3; \
    const int t0 = gi * TPB;

#define A_PRELOAD \
    bf16x8 Af[4][8]; \
    _Pragma("unroll") \
    for (int bt = 0; bt < 4; ++bt) \
        _Pragma("unroll") \
        for (int kk = 0; kk < 8; ++kk) \
            Af[bt][kk] = *(const bf16x8*)( \
                zp + ((((rg * 4 + bt) << 3) + kk) << 9) + (lane << 3));

#define ISSUE_Q(T, Q, BUF) do {                                               \
        _Pragma("unroll")                                                     \
        for (int _kq = 0; _kq < 2; ++_kq)                                     \
            _Pragma("unroll")                                                 \
            for (int _vt = 0; _vt < 2; ++_vt) {                               \
                const int _row = min((T) * 32 + _vt * 16 + l15, V - 1);       \
                const float* _p = vocab_W + _row * D + ((Q) * 2 + _kq) * 32 + g * 8; \
                qb[BUF][_kq * 4 + _vt * 2 + 0] = *(const f32x4*)(_p);         \
                qb[BUF][_kq * 4 + _vt * 2 + 1] = *(const f32x4*)(_p + 4);     \
            }                                                                 \
    } while (0)

#define ISSUE_BIAS(T, BUF) do {                                               \
        _Pragma("unroll")                                                     \
        for (int _vt = 0; _vt < 2; ++_vt)                                     \
            bias[BUF][_vt] = vocab_b[min((T) * 32 + _vt * 16 + l15, V - 1)];  \
    } while (0)

#define CVT8(va, vb_) ({ bf16x8 _r;                                           \
        _r[0] = (__bf16)(va)[0]; _r[1] = (__bf16)(va)[1];                     \
        _r[2] = (__bf16)(va)[2]; _r[3] = (__bf16)(va)[3];                     \
        _r[4] = (__bf16)(vb_)[0]; _r[5] = (__bf16)(vb_)[1];                   \
        _r[6] = (__bf16)(vb_)[2]; _r[7] = (__bf16)(vb_)[3]; _r; })

// ---------------------------------------------------------------------------
// K3 (real, v8 unchanged): wave-decoupled, reg-direct, counted-FIFO waits.
// ---------------------------------------------------------------------------
__global__ __launch_bounds__(64, 2) void k3_logits(
    const float* __restrict__ vocab_W, const float* __restrict__ vocab_b,
    const ushort_t* __restrict__ zp, float* __restrict__ partial)
{
    K3_PRELUDE
    A_PRELOAD
    f32x4 qb[2][8];
    float bias[2][2];
    float sacc[4][4] = {};

    ISSUE_BIAS(t0, 0);
    ISSUE_Q(t0, 0, 0);
    __builtin_amdgcn_sched_barrier(0);

    #pragma unroll
    for (int i = 0; i < TPB; ++i) {
        const int t = t0 + i;
        f32x4 acc[4][2] = {};
        #pragma unroll
        for (int q = 0; q < 4; ++q) {
            const int cur = q & 1, nxt = cur ^ 1;
            if (q < 3) {
                ISSUE_Q(t, q + 1, nxt);
                SWAIT(8);
            } else if (i < TPB - 1) {
                ISSUE_BIAS(t + 1, (i + 1) & 1);
                ISSUE_Q(t + 1, 0, nxt);
                SWAIT(10);
            } else {
                SWAIT(0);
            }
            #pragma unroll
            for (int kq = 0; kq < 2; ++kq) {
                const int kk = q * 2 + kq;
                const bf16x8 B0 = CVT8(qb[cur][kq * 4 + 0], qb[cur][kq * 4 + 1]);
                const bf16x8 B1 = CVT8(qb[cur][kq * 4 + 2], qb[cur][kq * 4 + 3]);
                #pragma unroll
                for (int bt = 0; bt < 4; ++bt) {
                    acc[bt][0] = __builtin_amdgcn_mfma_f32_16x16x32_bf16(
                        Af[bt][kk], B0, acc[bt][0], 0, 0, 0);
                    acc[bt][1] = __builtin_amdgcn_mfma_f32_16x16x32_bf16(
                        Af[bt][kk], B1, acc[bt][1], 0, 0, 0);
                }
            }
        }
        const int bb = i & 1;
        bool vld[2];
        #pragma unroll
        for (int vt = 0; vt < 2; ++vt)
            vld[vt] = (t * 32 + vt * 16 + l15) < V;
        #pragma unroll
        for (int bt = 0; bt < 4; ++bt)
            #pragma unroll
            for (int r = 0; r < 4; ++r) {
                float s = 0.f;
                #pragma unroll
                for (int vt = 0; vt < 2; ++vt)
                    s += vld[vt] ? __expf(acc[bt][vt][r] + bias[bb][vt]) : 0.f;
                sacc[bt][r] += s;
            }
    }

    #pragma unroll
    for (int bt = 0; bt < 4; ++bt)
        #pragma unroll
        for (int r = 0; r < 4; ++r) {
            float s = sacc[bt][r];
            s += __shfl_xor(s, 1); s += __shfl_xor(s, 2);
            s += __shfl_xor(s, 4); s += __shfl_xor(s, 8);
            if (l15 == 0) {
                const int brow = rg * 64 + bt * 16 + g * 4 + r;
                partial[brow * NBLK_OUT + gi] = s;
            }
        }
}

// ---------------------------------------------------------------------------
// PROBE 1: k3_noexp — identical to k3 but epilogue has NO __expf.
// ---------------------------------------------------------------------------
__global__ __launch_bounds__(64, 2) void k3_noexp(
    const float* __restrict__ vocab_W, const float* __restrict__ vocab_b,
    const ushort_t* __restrict__ zp, float* __restrict__ dummy)
{
    K3_PRELUDE
    A_PRELOAD
    f32x4 qb[2][8];
    float bias[2][2];
    float sacc[4][4] = {};

    ISSUE_BIAS(t0, 0);
    ISSUE_Q(t0, 0, 0);
    __builtin_amdgcn_sched_barrier(0);

    #pragma unroll
    for (int i = 0; i < TPB; ++i) {
        const int t = t0 + i;
        f32x4 acc[4][2] = {};
        #pragma unroll
        for (int q = 0; q < 4; ++q) {
            const int cur = q & 1, nxt = cur ^ 1;
            if (q < 3) { ISSUE_Q(t, q + 1, nxt); SWAIT(8); }
            else if (i < TPB - 1) { ISSUE_BIAS(t + 1, (i + 1) & 1); ISSUE_Q(t + 1, 0, nxt); SWAIT(10); }
            else { SWAIT(0); }
            #pragma unroll
            for (int kq = 0; kq < 2; ++kq) {
                const int kk = q * 2 + kq;
                const bf16x8 B0 = CVT8(qb[cur][kq * 4 + 0], qb[cur][kq * 4 + 1]);
                const bf16x8 B1 = CVT8(qb[cur][kq * 4 + 2], qb[cur][kq * 4 + 3]);
                #pragma unroll
                for (int bt = 0; bt < 4; ++bt) {
                    acc[bt][0] = __builtin_amdgcn_mfma_f32_16x16x32_bf16(
                        Af[bt][kk], B0, acc[bt][0], 0, 0, 0);
                    acc[bt][1] = __builtin_amdgcn_mfma_f32_16x16x32_bf16(
                        Af[bt][kk], B1, acc[bt][1], 0, 0, 0);
                }
            }
        }
        const int bb = i & 1;
        bool vld[2];
        #pragma unroll
        for (int vt = 0; vt < 2; ++vt)
            vld[vt] = (t * 32 + vt * 16 + l15) < V;
        #pragma unroll
        for (int bt = 0; bt < 4; ++bt)
            #pragma unroll
            for (int r = 0; r < 4; ++r) {
                float s = 0.f;
                #pragma unroll
                for (int vt = 0; vt < 2; ++vt)
                    s += vld[vt] ? (acc[bt][vt][r] + bias[bb][vt]) : 0.f;   // no exp
                sacc[bt][r] += s;
            }
    }

    #pragma unroll
    for (int bt = 0; bt < 4; ++bt)
        #pragma unroll
        for (int r = 0; r < 4; ++r) {
            float s = sacc[bt][r];
            s += __shfl_xor(s, 1); s += __shfl_xor(s, 2);
            s += __shfl_xor(s, 4); s += __shfl_xor(s, 8);
            if (l15 == 0) {
                const int brow = rg * 64 + bt * 16 + g * 4 + r;
                dummy[brow * NBLK_OUT + gi] = s;
            }
        }
}

// ---------------------------------------------------------------------------
// PROBE 2: k3_nomfma — identical loads + waits; MFMA/CVT replaced by
// full-width component sums (keeps every dwordx4 load live at full width).
// ---------------------------------------------------------------------------
__global__ __launch_bounds__(64, 2) void k3_nomfma(
    const float* __restrict__ vocab_W, const float* __restrict__ vocab_b,
    const ushort_t* __restrict__ zp, float* __restrict__ dummy)
{
    K3_PRELUDE
    A_PRELOAD
    f32x4 qb[2][8];
    float bias[2][2];
    float sinkf = 0.f;
    // keep A live
    #pragma unroll
    for (int bt = 0; bt < 4; ++bt)
        #pragma unroll
        for (int kk = 0; kk < 8; ++kk)
            sinkf += (float)Af[bt][kk][0];

    ISSUE_BIAS(t0, 0);
    ISSUE_Q(t0, 0, 0);
    __builtin_amdgcn_sched_barrier(0);

    float sacc[4][4] = {};
    #pragma unroll
    for (int i = 0; i < TPB; ++i) {
        const int t = t0 + i;
        #pragma unroll
        for (int q = 0; q < 4; ++q) {
            const int cur = q & 1, nxt = cur ^ 1;
            if (q < 3) { ISSUE_Q(t, q + 1, nxt); SWAIT(8); }
            else if (i < TPB - 1) { ISSUE_BIAS(t + 1, (i + 1) & 1); ISSUE_Q(t + 1, 0, nxt); SWAIT(10); }
            else { SWAIT(0); }
            #pragma unroll
            for (int j = 0; j < 8; ++j)
                sinkf += qb[cur][j][0] + qb[cur][j][1] + qb[cur][j][2] + qb[cur][j][3];
        }
        const int bb = i & 1;
        #pragma unroll
        for (int bt = 0; bt < 4; ++bt)
            #pragma unroll
            for (int r = 0; r < 4; ++r)
                sacc[bt][r] += bias[bb][0] + bias[bb][1];
    }

    #pragma unroll
    for (int bt = 0; bt < 4; ++bt)
        #pragma unroll
        for (int r = 0; r < 4; ++r) {
            float s = sacc[bt][r] + sinkf;
            s += __shfl_xor(s, 1); s += __shfl_xor(s, 2);
            s += __shfl_xor(s, 4); s += __shfl_xor(s, 8);
            if (l15 == 0) {
                const int brow = rg * 64 + bt * 16 + g * 4 + r;
                dummy[brow * NBLK_OUT + gi] = s;
            }
        }
}

// ---------------------------------------------------------------------------
// PROBE 3: k3_noload — A preload only; B forged from A regs; zero loop VMEM.
// Full MFMA count + exp epilogue + stores. Isolates the compute/issue path.
// ---------------------------------------------------------------------------
__global__ __launch_bounds__(64, 2) void k3_noload(
    const float* __restrict__ vocab_W, const float* __restrict__ vocab_b,
    const ushort_t* __restrict__ zp, float* __restrict__ dummy)
{
    K3_PRELUDE
    A_PRELOAD
    SWAIT(0);
    (void)vocab_W; (void)vocab_b;

    float sacc[4][4] = {};
    #pragma unroll
    for (int i = 0; i < TPB; ++i) {
        f32x4 acc[4][2] = {};
        #pragma unroll
        for (int q = 0; q < 4; ++q) {
            #pragma unroll
            for (int kq = 0; kq < 2; ++kq) {
                const int kk = q * 2 + kq;
                const bf16x8 B0 = Af[0][7 - kk];
                const bf16x8 B1 = Af[1][7 - kk];
                #pragma unroll
                for (int bt = 0; bt < 4; ++bt) {
                    acc[bt][0] = __builtin_amdgcn_mfma_f32_16x16x32_bf16(
                        Af[bt][kk], B0, acc[bt][0], 0, 0, 0);
                    acc[bt][1] = __builtin_amdgcn_mfma_f32_16x16x32_bf16(
                        Af[bt][kk], B1, acc[bt][1], 0, 0, 0);
                }
            }
        }
        #pragma unroll
        for (int bt = 0; bt < 4; ++bt)
            #pragma unroll
            for (int r = 0; r < 4; ++r) {
                float s = 0.f;
                #pragma unroll
                for (int vt = 0; vt < 2; ++vt)
                    s += __expf(acc[bt][vt][r] * 1e-6f + 1.0f);
                sacc[bt][r] += s;
            }
    }

    #pragma unroll
    for (int bt = 0; bt < 4; ++bt)
        #pragma unroll
        for (int r = 0; r < 4; ++r) {
            float s = sacc[bt][r];
            s += __shfl_xor(s, 1); s += __shfl_xor(s, 2);
            s += __shfl_xor(s, 4); s += __shfl_xor(s, 8);
            if (l15 == 0) {
                const int brow = rg * 64 + bt * 16 + g * 4 + r;
                dummy[brow * NBLK_OUT + gi] = s;
            }
        }
}

// ---------------------------------------------------------------------------
// PROBE 4: k3_stream — pure float4 grid-stride read of all vocab_W (51.2 MB).
// The roofline for this stream in this context.
// ---------------------------------------------------------------------------
__global__ __launch_bounds__(256) void k3_stream(
    const float* __restrict__ vocab_W, float* __restrict__ dummy)
{
    const int tid = blockIdx.x * 256 + threadIdx.x;
    const int stride = gridDim.x * 256;
    float s = 0.f;
    for (int i = tid; i < V * D / 4; i += stride) {
        const f32x4 v = ((const f32x4*)vocab_W)[i];
        s += v[0] + v[1] + v[2] + v[3];
    }
    s = wave_reduce(s);
    if ((threadIdx.x & 63) == 0)
        dummy[(blockIdx.x * 4) + (threadIdx.x >> 6)] = s;
}

#undef CVT8
#undef ISSUE_BIAS
#undef ISSUE_Q
#undef A_PRELOAD
#undef K3_PRELUDE

// ---------------------------------------------------------------------------
// K4 / K5 (unchanged, proven)
// ---------------------------------------------------------------------------
__global__ __launch_bounds__(256) void k4_lse(
    const float* __restrict__ partial, const float* __restrict__ base,
    float* __restrict__ outb)
{
    __shared__ float red[4];
    const int b = blockIdx.x, tid = threadIdx.x;
    float s = 0.f;
    for (int i = tid; i < NBLK_OUT; i += 256) s += partial[b * NBLK_OUT + i];
    s = wave_reduce(s);
    if ((tid & 63) == 0) red[tid >> 6] = s;
    __syncthreads();
    if (tid == 0) {
        const float tot = red[0] + red[1] + red[2] + red[3];
        outb[b] = base[b] - (float)C * __logf(tot);
    }
}

__global__ __launch_bounds__(256) void k5_final(
    const float* __restrict__ outb, float* __restrict__ out)
{
    __shared__ float red[4];
    const int tid = threadIdx.x;
    float s = outb[tid];
    s = wave_reduce(s);
    if ((tid & 63) == 0) red[tid >> 6] = s;
    __syncthreads();
    if (tid == 0) out[0] = red[0] + red[1] + red[2] + red[3];
}

extern "C" void kernel_launch(void* const* d_in, const int* in_sizes, int n_in,
                              void* d_out, int out_size, void* d_ws, size_t ws_size,
                              hipStream_t stream)
{
    const int*   center_id     = (const int*)d_in[0];
    const int*   context_ids   = (const int*)d_in[1];
    const float* embeddings    = (const float*)d_in[2];
    const float* prior_means_w = (const float*)d_in[3];
    const float* prior_vars_w  = (const float*)d_in[4];
    const float* enc_W         = (const float*)d_in[5];
    const float* enc_b         = (const float*)d_in[6];
    const float* mean_W        = (const float*)d_in[7];
    const float* mean_b        = (const float*)d_in[8];
    const float* var_W         = (const float*)d_in[9];
    const float* var_b         = (const float*)d_in[10];
    const float* vocab_W       = (const float*)d_in[11];
    const float* vocab_b       = (const float*)d_in[12];
    const float* epsilon       = (const float*)d_in[13];

    char* ws = (char*)d_ws;
    ushort_t* xbf     = (ushort_t*)ws;  ws += (size_t)MPAD * TWO_D * 2;   // 4 MB
    ushort_t* h_bf    = (ushort_t*)ws;  ws += (size_t)B * TWO_D * 2;      // 256 KB
    float*    mv      = (float*)ws;     ws += (size_t)B * TWO_D * 4;      // 512 KB
    ushort_t* zp      = (ushort_t*)ws;  ws += (size_t)B * D * 2;          // 128 KB
    float*    base    = (float*)ws;     ws += B * 4;
    float*    outb    = (float*)ws;     ws += B * 4;
    float*    partial = (float*)ws;     ws += (size_t)B * NGI * 4;        // 533 KB
    float*    dummy   = (float*)ws;                                       // 533 KB probes

    hipLaunchKernelGGL(k0_gather, dim3(2048), dim3(256), 0, stream,
                       center_id, context_ids, embeddings, xbf);
    hipLaunchKernelGGL(k_enc, dim3(512), dim3(256), 0, stream,
                       enc_W, enc_b, xbf, h_bf);
    hipLaunchKernelGGL(k_heads, dim3(32), dim3(256), 0, stream,
                       mean_W, mean_b, var_W, var_b, h_bf, mv);
    hipLaunchKernelGGL(k_z, dim3(B), dim3(256), 0, stream,
                       center_id, context_ids, prior_means_w, prior_vars_w,
                       vocab_W, vocab_b, epsilon, mv, zp, base);
    hipLaunchKernelGGL(k3_logits, dim3(4 * NGI), dim3(64), 0, stream,
                       vocab_W, vocab_b, zp, partial);
    // --- ablation probes (outputs discarded; diagnosis only) ---
    hipLaunchKernelGGL(k3_noexp,  dim3(4 * NGI), dim3(64), 0, stream,
                       vocab_W, vocab_b, zp, dummy);
    hipLaunchKernelGGL(k3_nomfma, dim3(4 * NGI), dim3(64), 0, stream,
                       vocab_W, vocab_b, zp, dummy);
    hipLaunchKernelGGL(k3_noload, dim3(4 * NGI), dim3(64), 0, stream,
                       vocab_W, vocab_b, zp, dummy);
    hipLaunchKernelGGL(k3_stream, dim3(1024), dim3(256), 0, stream,
                       vocab_W, dummy);
    // --- end probes ---
    hipLaunchKernelGGL(k4_lse, dim3(B), dim3(256), 0, stream, partial, base, outb);
    hipLaunchKernelGGL(k5_final, dim3(1), dim3(256), 0, stream, outb, (float*)d_out);
}

// Round 10
// 161.687 us; speedup vs baseline: 1.0990x; 1.0990x over previous
//
#include <hip/hip_runtime.h>
#include <hip/hip_bf16.h>

// Sizes fixed by the reference
#define V 50000
#define D 256
#define B 256
#define C 10
#define TWO_D 512
#define VBLK 32
#define NGI 1563                       // one 32-row vocab tile per wave
#define PCOLS (2 * NGI)                // partial columns: (gi, vt)
#define MPAD 4096                      // 256 b * 16 (c padded 10 -> 16)

typedef __bf16 bf16x8 __attribute__((ext_vector_type(8)));
typedef float f32x4 __attribute__((ext_vector_type(4)));
typedef unsigned short ushort_t;
typedef unsigned int uint_t;

__device__ inline ushort_t f2bf(float f) {
    uint_t u = __builtin_bit_cast(uint_t, f);
    uint_t r = (u + 0x7FFFu + ((u >> 16) & 1u)) >> 16;
    return (ushort_t)r;
}

__device__ inline float softplus_f(float x) {
    return (x > 0.f) ? (x + log1pf(__expf(-x))) : log1pf(__expf(x));
}

__device__ inline float wave_reduce(float v) {
    #pragma unroll
    for (int m = 1; m < 64; m <<= 1) v += __shfl_xor(v, m);
    return v;
}

// counted vmcnt wait (inline asm; memory clobber pins load issue order)
#define SWAIT(N) do { \
    asm volatile("s_waitcnt vmcnt(" #N ")" ::: "memory"); \
    __builtin_amdgcn_sched_barrier(0); \
} while (0)

// ---------------------------------------------------------------------------
// K0 (unchanged, proven)
// ---------------------------------------------------------------------------
__global__ __launch_bounds__(256) void k0_gather(
    const int* __restrict__ center_id, const int* __restrict__ context_ids,
    const float* __restrict__ embeddings, ushort_t* __restrict__ xbf)
{
    const int idx = blockIdx.x * 256 + threadIdx.x;
    const int m = idx >> 7;
    const int q = idx & 127;
    const int k = q * 4;
    const int b = m >> 4, c = m & 15;
    ushort4 o;
    if (k < D) {
        const float4 v = *(const float4*)(embeddings + center_id[b] * D + k);
        o.x = f2bf(v.x); o.y = f2bf(v.y); o.z = f2bf(v.z); o.w = f2bf(v.w);
    } else if (c < C) {
        const float4 v = *(const float4*)(embeddings + context_ids[b * C + c] * D + (k - D));
        o.x = f2bf(v.x); o.y = f2bf(v.y); o.z = f2bf(v.z); o.w = f2bf(v.w);
    } else {
        o.x = 0; o.y = 0; o.z = 0; o.w = 0;
    }
    *(ushort4*)(xbf + idx * 4) = o;
}

// ---------------------------------------------------------------------------
// K_enc (unchanged, proven)
// ---------------------------------------------------------------------------
__global__ __launch_bounds__(256) void k_enc(
    const float* __restrict__ enc_W, const float* __restrict__ enc_b,
    const ushort_t* __restrict__ xbf, ushort_t* __restrict__ h_bf)
{
    __shared__ __align__(16) ushort_t wt[2][64 * 40];
    const int tid = threadIdx.x;
    const int mblk = blockIdx.x & 63;
    const int nblk = blockIdx.x >> 6;
    const int n0 = nblk * 64;
    const int wid = tid >> 6, lane = tid & 63;
    const int l15 = lane & 15, g = lane >> 4;

    const int r0 = tid >> 3, kq = tid & 7, r1 = r0 + 32;
    const float* src0 = enc_W + (n0 + r0) * TWO_D + kq * 4;
    const float* src1 = enc_W + (n0 + r1) * TWO_D + kq * 4;
    const int dst0 = r0 * 40 + kq * 4;
    const int dst1 = r1 * 40 + kq * 4;

    {
        const float4 na = *(const float4*)(src0);
        const float4 nb = *(const float4*)(src1);
        ushort4 pa, pb;
        pa.x = f2bf(na.x); pa.y = f2bf(na.y); pa.z = f2bf(na.z); pa.w = f2bf(na.w);
        pb.x = f2bf(nb.x); pb.y = f2bf(nb.y); pb.z = f2bf(nb.z); pb.w = f2bf(nb.w);
        *(ushort4*)(&wt[0][dst0]) = pa;
        *(ushort4*)(&wt[0][dst1]) = pb;
    }
    __syncthreads();

    const int rowA = mblk * 64 + wid * 16 + l15;
    f32x4 acc[4] = {};
    #pragma unroll 1
    for (int kk = 0; kk < 16; ++kk) {
        const int cur = kk & 1, nxt = cur ^ 1;
        float4 na, nb;
        if (kk < 15) {
            na = *(const float4*)(src0 + (kk + 1) * 32);
            nb = *(const float4*)(src1 + (kk + 1) * 32);
        }
        const bf16x8 A = *(const bf16x8*)(xbf + rowA * TWO_D + kk * 32 + g * 8);
        bf16x8 Bf[4];
        #pragma unroll
        for (int vt = 0; vt < 4; ++vt)
            Bf[vt] = *(const bf16x8*)(&wt[cur][(vt * 16 + l15) * 40 + g * 8]);
        #pragma unroll
        for (int vt = 0; vt < 4; ++vt)
            acc[vt] = __builtin_amdgcn_mfma_f32_16x16x32_bf16(A, Bf[vt], acc[vt], 0, 0, 0);
        if (kk < 15) {
            ushort4 pa, pb;
            pa.x = f2bf(na.x); pa.y = f2bf(na.y); pa.z = f2bf(na.z); pa.w = f2bf(na.w);
            pb.x = f2bf(nb.x); pb.y = f2bf(nb.y); pb.z = f2bf(nb.z); pb.w = f2bf(nb.w);
            *(ushort4*)(&wt[nxt][dst0]) = pa;
            *(ushort4*)(&wt[nxt][dst1]) = pb;
        }
        __syncthreads();
    }

    const int b = mblk * 4 + wid;
    #pragma unroll
    for (int vt = 0; vt < 4; ++vt) {
        const int j = n0 + vt * 16 + l15;
        const float bias = enc_b[j];
        float s = 0.f;
        #pragma unroll
        for (int r = 0; r < 4; ++r) {
            const int c = g * 4 + r;
            const float vv = acc[vt][r] + bias;
            s += (c < C) ? fmaxf(vv, 0.f) : 0.f;
        }
        s += __shfl_xor(s, 16);
        s += __shfl_xor(s, 32);
        if (g == 0) h_bf[b * TWO_D + j] = f2bf(s);
    }
}

// ---------------------------------------------------------------------------
// K_heads (unchanged, proven)
// ---------------------------------------------------------------------------
__global__ __launch_bounds__(256) void k_heads(
    const float* __restrict__ mean_W, const float* __restrict__ mean_b,
    const float* __restrict__ var_W, const float* __restrict__ var_b,
    const ushort_t* __restrict__ h_bf, float* __restrict__ mv)
{
    __shared__ __align__(16) ushort_t wt[2][64 * 40];
    const int tid = threadIdx.x;
    const int mblk = blockIdx.x & 3;
    const int nblk = blockIdx.x >> 2;
    const int n0 = nblk * 64;
    const float* Wsrc = (nblk < 4) ? mean_W : var_W;
    const float* bsrc = (nblk < 4) ? mean_b : var_b;
    const int nloc = (nblk & 3) * 64;
    const int wid = tid >> 6, lane = tid & 63;
    const int l15 = lane & 15, g = lane >> 4;

    const int r0 = tid >> 3, kq = tid & 7, r1 = r0 + 32;
    const float* src0 = Wsrc + (nloc + r0) * TWO_D + kq * 4;
    const float* src1 = Wsrc + (nloc + r1) * TWO_D + kq * 4;
    const int dst0 = r0 * 40 + kq * 4;
    const int dst1 = r1 * 40 + kq * 4;

    {
        const float4 na = *(const float4*)(src0);
        const float4 nb = *(const float4*)(src1);
        ushort4 pa, pb;
        pa.x = f2bf(na.x); pa.y = f2bf(na.y); pa.z = f2bf(na.z); pa.w = f2bf(na.w);
        pb.x = f2bf(nb.x); pb.y = f2bf(nb.y); pb.z = f2bf(nb.z); pb.w = f2bf(nb.w);
        *(ushort4*)(&wt[0][dst0]) = pa;
        *(ushort4*)(&wt[0][dst1]) = pb;
    }
    __syncthreads();

    const int rowA = mblk * 64 + wid * 16 + l15;
    f32x4 acc[4] = {};
    #pragma unroll 1
    for (int kk = 0; kk < 16; ++kk) {
        const int cur = kk & 1, nxt = cur ^ 1;
        float4 na, nb;
        if (kk < 15) {
            na = *(const float4*)(src0 + (kk + 1) * 32);
            nb = *(const float4*)(src1 + (kk + 1) * 32);
        }
        const bf16x8 A = *(const bf16x8*)(h_bf + rowA * TWO_D + kk * 32 + g * 8);
        bf16x8 Bf[4];
        #pragma unroll
        for (int vt = 0; vt < 4; ++vt)
            Bf[vt] = *(const bf16x8*)(&wt[cur][(vt * 16 + l15) * 40 + g * 8]);
        #pragma unroll
        for (int vt = 0; vt < 4; ++vt)
            acc[vt] = __builtin_amdgcn_mfma_f32_16x16x32_bf16(A, Bf[vt], acc[vt], 0, 0, 0);
        if (kk < 15) {
            ushort4 pa, pb;
            pa.x = f2bf(na.x); pa.y = f2bf(na.y); pa.z = f2bf(na.z); pa.w = f2bf(na.w);
            pb.x = f2bf(nb.x); pb.y = f2bf(nb.y); pb.z = f2bf(nb.z); pb.w = f2bf(nb.w);
            *(ushort4*)(&wt[nxt][dst0]) = pa;
            *(ushort4*)(&wt[nxt][dst1]) = pb;
        }
        __syncthreads();
    }

    const int rowBase = mblk * 64 + wid * 16;
    #pragma unroll
    for (int vt = 0; vt < 4; ++vt) {
        const int col = n0 + vt * 16 + l15;
        const float bias = bsrc[nloc + vt * 16 + l15];
        #pragma unroll
        for (int r = 0; r < 4; ++r) {
            const int row = rowBase + g * 4 + r;
            mv[row * TWO_D + col] = acc[vt][r] + bias;
        }
    }
}

// ---------------------------------------------------------------------------
// K_z (unchanged — packed zp write, proven)
// ---------------------------------------------------------------------------
__global__ __launch_bounds__(256) void k_z(
    const int* __restrict__ center_id, const int* __restrict__ context_ids,
    const float* __restrict__ prior_means_w, const float* __restrict__ prior_vars_w,
    const float* __restrict__ vocab_W, const float* __restrict__ vocab_b,
    const float* __restrict__ epsilon, const float* __restrict__ mv,
    ushort_t* __restrict__ zp, float* __restrict__ base)
{
    __shared__ float red[8];
    __shared__ int cids[C];
    const int b = blockIdx.x, tid = threadIdx.x;
    const int cid = center_id[b];
    if (tid < C) cids[tid] = context_ids[b * C + tid];
    __syncthreads();

    const int i = tid;
    const float mean = mv[b * TWO_D + i];
    const float a    = mv[b * TWO_D + D + i];
    const float var  = softplus_f(a);
    const float z    = mean + __expf(0.5f * var) * epsilon[i];

    {
        const int mt  = b >> 4;
        const int kkz = i >> 5;
        const int lz  = ((i >> 3) & 3) * 16 + (b & 15);
        zp[(mt * 8 + kkz) * 512 + lz * 8 + (i & 7)] = f2bf(z);
    }

    const float pm = prior_means_w[cid * D + i];
    const float pv = softplus_f(prior_vars_w[cid * D + i]);
    const float dm = pm - mean;
    float klt = var / pv + dm * dm / pv - 1.f + __logf(pv) - __logf(var);

    float wsum = 0.f;
    #pragma unroll
    for (int c = 0; c < C; ++c) wsum += vocab_W[cids[c] * D + i];
    float p = z * wsum;

    klt = wave_reduce(klt);
    p = wave_reduce(p);
    const int wid = tid >> 6, lane = tid & 63;
    if (lane == 0) { red[wid] = klt; red[4 + wid] = p; }
    __syncthreads();
    if (tid == 0) {
        const float kl = 0.5f * (red[0] + red[1] + red[2] + red[3]);
        float cs = red[4] + red[5] + red[6] + red[7];
        #pragma unroll
        for (int c = 0; c < C; ++c) cs += vocab_b[cids[c]];
        base[b] = cs - kl;
    }
}

// ---------------------------------------------------------------------------
// K3 (v9): v8's memory structure WITHOUT duplication.
// Grid 1563 x 64 thr (1 wave). Each wave owns ONE 32-row vocab tile and
// computes ALL 256 z-rows against it. Zero LDS, zero barriers; plain
// dwordx4 loads; counted FIFO vmcnt, never drained except pipeline end.
// B: fp32 staged in 4 rolling quarters -> full tile as bf16 in 64 VGPRs.
// A: streamed from packed zp (L2-hot, 1KB wave-contiguous chunks), depth-2
// rotating buffer (Ab[3][8]), vt-outer so acc = 16 x f32x4 (64 VGPR).
// Stores: 1KB contiguous per (gi, vt) -> no write-allocate scatter.
// ---------------------------------------------------------------------------
__global__ __launch_bounds__(64) void k3_logits(
    const float* __restrict__ vocab_W, const float* __restrict__ vocab_b,
    const ushort_t* __restrict__ zp, float* __restrict__ partial)
{
    const int lane = threadIdx.x;
    const int l15 = lane & 15, g = lane >> 4;
    const int gi = blockIdx.x;

    f32x4 qb[2][8];
    bf16x8 Bb[8][2];
    bf16x8 Ab[3][8];
    float bias[2];
    bool vld[2];

#define ISSUE_BIAS() do {                                                     \
        _Pragma("unroll")                                                     \
        for (int _vt = 0; _vt < 2; ++_vt) {                                   \
            const int _v = gi * VBLK + _vt * 16 + l15;                        \
            vld[_vt] = (_v < V);                                              \
            bias[_vt] = vocab_b[min(_v, V - 1)];                              \
        }                                                                     \
    } while (0)

#define ISSUE_Q(Q, BUF) do {                                                  \
        _Pragma("unroll")                                                     \
        for (int _kq = 0; _kq < 2; ++_kq)                                     \
            _Pragma("unroll")                                                 \
            for (int _vt = 0; _vt < 2; ++_vt) {                               \
                const int _row = min(gi * VBLK + _vt * 16 + l15, V - 1);      \
                const float* _p = vocab_W + _row * D + ((Q) * 2 + _kq) * 32 + g * 8; \
                qb[BUF][_kq * 4 + _vt * 2 + 0] = *(const f32x4*)(_p);         \
                qb[BUF][_kq * 4 + _vt * 2 + 1] = *(const f32x4*)(_p + 4);     \
            }                                                                 \
    } while (0)

#define CVT8(va, vb_) ({ bf16x8 _r;                                           \
        _r[0] = (__bf16)(va)[0]; _r[1] = (__bf16)(va)[1];                     \
        _r[2] = (__bf16)(va)[2]; _r[3] = (__bf16)(va)[3];                     \
        _r[4] = (__bf16)(vb_)[0]; _r[5] = (__bf16)(vb_)[1];                   \
        _r[6] = (__bf16)(vb_)[2]; _r[7] = (__bf16)(vb_)[3]; _r; })

#define CVT_Q(Q, BUF) do {                                                    \
        _Pragma("unroll")                                                     \
        for (int _kq = 0; _kq < 2; ++_kq) {                                   \
            Bb[(Q) * 2 + _kq][0] = CVT8(qb[BUF][_kq * 4 + 0], qb[BUF][_kq * 4 + 1]); \
            Bb[(Q) * 2 + _kq][1] = CVT8(qb[BUF][_kq * 4 + 2], qb[BUF][_kq * 4 + 3]); \
        }                                                                     \
    } while (0)

#define ISSUE_A(IDX, BUF) do {                                                \
        _Pragma("unroll")                                                     \
        for (int _kk = 0; _kk < 8; ++_kk)                                     \
            Ab[BUF][_kk] = *(const bf16x8*)(                                  \
                zp + ((((IDX) << 3) + _kk) << 9) + (lane << 3));              \
    } while (0)

    // ---- B staging: bias(2), Q0(8), Q1(8) -> rolled waits, cvt to Bb
    ISSUE_BIAS();
    ISSUE_Q(0, 0);
    ISSUE_Q(1, 1);
    SWAIT(8);               // bias + Q0 landed (<=8 remain = Q1)
    CVT_Q(0, 0);
    ISSUE_Q(2, 0);
    SWAIT(8);               // Q1 landed
    CVT_Q(1, 1);
    ISSUE_Q(3, 1);
    SWAIT(8);               // Q2 landed
    CVT_Q(2, 0);
    ISSUE_A(0, 0);          // A prefetch starts under Q3 flight
    ISSUE_A(1, 1);
    SWAIT(16);              // Q3 landed (<=16 remain = A0 + A1)
    CVT_Q(3, 1);

    // ---- compute: vt-outer, 16 bt per vt, depth-2 A prefetch (32 steps)
    #pragma unroll
    for (int vt = 0; vt < 2; ++vt) {
        f32x4 acc[16] = {};
        #pragma unroll
        for (int bt = 0; bt < 16; ++bt) {
            const int s = vt * 16 + bt;
            if (s < 30) {
                ISSUE_A((s + 2) & 15, (s + 2) % 3);
                SWAIT(16);                      // A[s] landed
            } else if (s == 30) {
                SWAIT(8);                       // A[30] landed
            } else {
                SWAIT(0);                       // A[31] landed
            }
            const int cur = s % 3;
            #pragma unroll
            for (int kk = 0; kk < 8; ++kk)
                acc[bt] = __builtin_amdgcn_mfma_f32_16x16x32_bf16(
                    Ab[cur][kk], Bb[kk][vt], acc[bt], 0, 0, 0);
        }
        // epilogue for this vt (overlaps next vt's A-load flight)
        #pragma unroll
        for (int bt = 0; bt < 16; ++bt)
            #pragma unroll
            for (int r = 0; r < 4; ++r) {
                float s = vld[vt] ? __expf(acc[bt][r] + bias[vt]) : 0.f;
                s += __shfl_xor(s, 1); s += __shfl_xor(s, 2);
                s += __shfl_xor(s, 4); s += __shfl_xor(s, 8);
                if (l15 == 0)
                    partial[(gi * 2 + vt) * 256 + bt * 16 + g * 4 + r] = s;
            }
    }

#undef ISSUE_A
#undef CVT_Q
#undef CVT8
#undef ISSUE_Q
#undef ISSUE_BIAS
}

// ---------------------------------------------------------------------------
// K4 (new layout): partial is [PCOLS][256]; 16 blocks, each owns 16 b's.
// Thread (tid): b = beta*16 + (tid&15), strides i over rows -> coalesced.
// ---------------------------------------------------------------------------
__global__ __launch_bounds__(256) void k4_lse(
    const float* __restrict__ partial, const float* __restrict__ base,
    float* __restrict__ outb)
{
    __shared__ float red[64];
    const int beta = blockIdx.x;
    const int tid = threadIdx.x;
    const int b = beta * 16 + (tid & 15);
    float s = 0.f;
    for (int i = tid >> 4; i < PCOLS; i += 16)
        s += partial[i * 256 + b];
    s += __shfl_xor(s, 16);
    s += __shfl_xor(s, 32);
    const int wid = tid >> 6, lane = tid & 63;
    if (lane < 16) red[wid * 16 + lane] = s;
    __syncthreads();
    if (tid < 16) {
        const float tot = red[tid] + red[16 + tid] + red[32 + tid] + red[48 + tid];
        outb[beta * 16 + tid] = base[beta * 16 + tid] - (float)C * __logf(tot);
    }
}

// ---------------------------------------------------------------------------
// K5 (unchanged, proven)
// ---------------------------------------------------------------------------
__global__ __launch_bounds__(256) void k5_final(
    const float* __restrict__ outb, float* __restrict__ out)
{
    __shared__ float red[4];
    const int tid = threadIdx.x;
    float s = outb[tid];
    s = wave_reduce(s);
    if ((tid & 63) == 0) red[tid >> 6] = s;
    __syncthreads();
    if (tid == 0) out[0] = red[0] + red[1] + red[2] + red[3];
}

extern "C" void kernel_launch(void* const* d_in, const int* in_sizes, int n_in,
                              void* d_out, int out_size, void* d_ws, size_t ws_size,
                              hipStream_t stream)
{
    const int*   center_id     = (const int*)d_in[0];
    const int*   context_ids   = (const int*)d_in[1];
    const float* embeddings    = (const float*)d_in[2];
    const float* prior_means_w = (const float*)d_in[3];
    const float* prior_vars_w  = (const float*)d_in[4];
    const float* enc_W         = (const float*)d_in[5];
    const float* enc_b         = (const float*)d_in[6];
    const float* mean_W        = (const float*)d_in[7];
    const float* mean_b        = (const float*)d_in[8];
    const float* var_W         = (const float*)d_in[9];
    const float* var_b         = (const float*)d_in[10];
    const float* vocab_W       = (const float*)d_in[11];
    const float* vocab_b       = (const float*)d_in[12];
    const float* epsilon       = (const float*)d_in[13];

    char* ws = (char*)d_ws;
    ushort_t* xbf     = (ushort_t*)ws;  ws += (size_t)MPAD * TWO_D * 2;   // 4 MB
    ushort_t* h_bf    = (ushort_t*)ws;  ws += (size_t)B * TWO_D * 2;      // 256 KB
    float*    mv      = (float*)ws;     ws += (size_t)B * TWO_D * 4;      // 512 KB
    ushort_t* zp      = (ushort_t*)ws;  ws += (size_t)B * D * 2;          // 128 KB
    float*    base    = (float*)ws;     ws += B * 4;
    float*    outb    = (float*)ws;     ws += B * 4;
    float*    partial = (float*)ws;                                       // 3.2 MB

    hipLaunchKernelGGL(k0_gather, dim3(2048), dim3(256), 0, stream,
                       center_id, context_ids, embeddings, xbf);
    hipLaunchKernelGGL(k_enc, dim3(512), dim3(256), 0, stream,
                       enc_W, enc_b, xbf, h_bf);
    hipLaunchKernelGGL(k_heads, dim3(32), dim3(256), 0, stream,
                       mean_W, mean_b, var_W, var_b, h_bf, mv);
    hipLaunchKernelGGL(k_z, dim3(B), dim3(256), 0, stream,
                       center_id, context_ids, prior_means_w, prior_vars_w,
                       vocab_W, vocab_b, epsilon, mv, zp, base);
    hipLaunchKernelGGL(k3_logits, dim3(NGI), dim3(64), 0, stream,
                       vocab_W, vocab_b, zp, partial);
    hipLaunchKernelGGL(k4_lse, dim3(16), dim3(256), 0, stream, partial, base, outb);
    hipLaunchKernelGGL(k5_final, dim3(1), dim3(256), 0, stream, outb, (float*)d_out);
}

// Round 11
// 126.382 us; speedup vs baseline: 1.4060x; 1.2794x over previous
//
#include <hip/hip_runtime.h>
#include <hip/hip_bf16.h>

// Sizes fixed by the reference
#define V 50000
#define D 256
#define B 256
#define C 10
#define TWO_D 512
#define VBLK 64
#define NBLK ((V + VBLK - 1) / VBLK)   // 782
#define PCOLS (NBLK * 4)               // 3128 partial columns (blk, vt)
#define MPAD 4096                      // 256 b * 16 (c padded 10 -> 16)

typedef __bf16 bf16x8 __attribute__((ext_vector_type(8)));
typedef float f32x4 __attribute__((ext_vector_type(4)));
typedef unsigned short ushort_t;
typedef unsigned int uint_t;

__device__ inline ushort_t f2bf(float f) {
    uint_t u = __builtin_bit_cast(uint_t, f);
    uint_t r = (u + 0x7FFFu + ((u >> 16) & 1u)) >> 16;
    return (ushort_t)r;
}

__device__ inline float softplus_f(float x) {
    return (x > 0.f) ? (x + log1pf(__expf(-x))) : log1pf(__expf(x));
}

__device__ inline float wave_reduce(float v) {
    #pragma unroll
    for (int m = 1; m < 64; m <<= 1) v += __shfl_xor(v, m);
    return v;
}

// ---------------------------------------------------------------------------
// K0 (unchanged, proven)
// ---------------------------------------------------------------------------
__global__ __launch_bounds__(256) void k0_gather(
    const int* __restrict__ center_id, const int* __restrict__ context_ids,
    const float* __restrict__ embeddings, ushort_t* __restrict__ xbf)
{
    const int idx = blockIdx.x * 256 + threadIdx.x;
    const int m = idx >> 7;
    const int q = idx & 127;
    const int k = q * 4;
    const int b = m >> 4, c = m & 15;
    ushort4 o;
    if (k < D) {
        const float4 v = *(const float4*)(embeddings + center_id[b] * D + k);
        o.x = f2bf(v.x); o.y = f2bf(v.y); o.z = f2bf(v.z); o.w = f2bf(v.w);
    } else if (c < C) {
        const float4 v = *(const float4*)(embeddings + context_ids[b * C + c] * D + (k - D));
        o.x = f2bf(v.x); o.y = f2bf(v.y); o.z = f2bf(v.z); o.w = f2bf(v.w);
    } else {
        o.x = 0; o.y = 0; o.z = 0; o.w = 0;
    }
    *(ushort4*)(xbf + idx * 4) = o;
}

// ---------------------------------------------------------------------------
// K_enc (unchanged, proven)
// ---------------------------------------------------------------------------
__global__ __launch_bounds__(256) void k_enc(
    const float* __restrict__ enc_W, const float* __restrict__ enc_b,
    const ushort_t* __restrict__ xbf, ushort_t* __restrict__ h_bf)
{
    __shared__ __align__(16) ushort_t wt[2][64 * 40];
    const int tid = threadIdx.x;
    const int mblk = blockIdx.x & 63;
    const int nblk = blockIdx.x >> 6;
    const int n0 = nblk * 64;
    const int wid = tid >> 6, lane = tid & 63;
    const int l15 = lane & 15, g = lane >> 4;

    const int r0 = tid >> 3, kq = tid & 7, r1 = r0 + 32;
    const float* src0 = enc_W + (n0 + r0) * TWO_D + kq * 4;
    const float* src1 = enc_W + (n0 + r1) * TWO_D + kq * 4;
    const int dst0 = r0 * 40 + kq * 4;
    const int dst1 = r1 * 40 + kq * 4;

    {
        const float4 na = *(const float4*)(src0);
        const float4 nb = *(const float4*)(src1);
        ushort4 pa, pb;
        pa.x = f2bf(na.x); pa.y = f2bf(na.y); pa.z = f2bf(na.z); pa.w = f2bf(na.w);
        pb.x = f2bf(nb.x); pb.y = f2bf(nb.y); pb.z = f2bf(nb.z); pb.w = f2bf(nb.w);
        *(ushort4*)(&wt[0][dst0]) = pa;
        *(ushort4*)(&wt[0][dst1]) = pb;
    }
    __syncthreads();

    const int rowA = mblk * 64 + wid * 16 + l15;
    f32x4 acc[4] = {};
    #pragma unroll 1
    for (int kk = 0; kk < 16; ++kk) {
        const int cur = kk & 1, nxt = cur ^ 1;
        float4 na, nb;
        if (kk < 15) {
            na = *(const float4*)(src0 + (kk + 1) * 32);
            nb = *(const float4*)(src1 + (kk + 1) * 32);
        }
        const bf16x8 A = *(const bf16x8*)(xbf + rowA * TWO_D + kk * 32 + g * 8);
        bf16x8 Bf[4];
        #pragma unroll
        for (int vt = 0; vt < 4; ++vt)
            Bf[vt] = *(const bf16x8*)(&wt[cur][(vt * 16 + l15) * 40 + g * 8]);
        #pragma unroll
        for (int vt = 0; vt < 4; ++vt)
            acc[vt] = __builtin_amdgcn_mfma_f32_16x16x32_bf16(A, Bf[vt], acc[vt], 0, 0, 0);
        if (kk < 15) {
            ushort4 pa, pb;
            pa.x = f2bf(na.x); pa.y = f2bf(na.y); pa.z = f2bf(na.z); pa.w = f2bf(na.w);
            pb.x = f2bf(nb.x); pb.y = f2bf(nb.y); pb.z = f2bf(nb.z); pb.w = f2bf(nb.w);
            *(ushort4*)(&wt[nxt][dst0]) = pa;
            *(ushort4*)(&wt[nxt][dst1]) = pb;
        }
        __syncthreads();
    }

    const int b = mblk * 4 + wid;
    #pragma unroll
    for (int vt = 0; vt < 4; ++vt) {
        const int j = n0 + vt * 16 + l15;
        const float bias = enc_b[j];
        float s = 0.f;
        #pragma unroll
        for (int r = 0; r < 4; ++r) {
            const int c = g * 4 + r;
            const float vv = acc[vt][r] + bias;
            s += (c < C) ? fmaxf(vv, 0.f) : 0.f;
        }
        s += __shfl_xor(s, 16);
        s += __shfl_xor(s, 32);
        if (g == 0) h_bf[b * TWO_D + j] = f2bf(s);
    }
}

// ---------------------------------------------------------------------------
// K_heads (unchanged, proven)
// ---------------------------------------------------------------------------
__global__ __launch_bounds__(256) void k_heads(
    const float* __restrict__ mean_W, const float* __restrict__ mean_b,
    const float* __restrict__ var_W, const float* __restrict__ var_b,
    const ushort_t* __restrict__ h_bf, float* __restrict__ mv)
{
    __shared__ __align__(16) ushort_t wt[2][64 * 40];
    const int tid = threadIdx.x;
    const int mblk = blockIdx.x & 3;
    const int nblk = blockIdx.x >> 2;
    const int n0 = nblk * 64;
    const float* Wsrc = (nblk < 4) ? mean_W : var_W;
    const float* bsrc = (nblk < 4) ? mean_b : var_b;
    const int nloc = (nblk & 3) * 64;
    const int wid = tid >> 6, lane = tid & 63;
    const int l15 = lane & 15, g = lane >> 4;

    const int r0 = tid >> 3, kq = tid & 7, r1 = r0 + 32;
    const float* src0 = Wsrc + (nloc + r0) * TWO_D + kq * 4;
    const float* src1 = Wsrc + (nloc + r1) * TWO_D + kq * 4;
    const int dst0 = r0 * 40 + kq * 4;
    const int dst1 = r1 * 40 + kq * 4;

    {
        const float4 na = *(const float4*)(src0);
        const float4 nb = *(const float4*)(src1);
        ushort4 pa, pb;
        pa.x = f2bf(na.x); pa.y = f2bf(na.y); pa.z = f2bf(na.z); pa.w = f2bf(na.w);
        pb.x = f2bf(nb.x); pb.y = f2bf(nb.y); pb.z = f2bf(nb.z); pb.w = f2bf(nb.w);
        *(ushort4*)(&wt[0][dst0]) = pa;
        *(ushort4*)(&wt[0][dst1]) = pb;
    }
    __syncthreads();

    const int rowA = mblk * 64 + wid * 16 + l15;
    f32x4 acc[4] = {};
    #pragma unroll 1
    for (int kk = 0; kk < 16; ++kk) {
        const int cur = kk & 1, nxt = cur ^ 1;
        float4 na, nb;
        if (kk < 15) {
            na = *(const float4*)(src0 + (kk + 1) * 32);
            nb = *(const float4*)(src1 + (kk + 1) * 32);
        }
        const bf16x8 A = *(const bf16x8*)(h_bf + rowA * TWO_D + kk * 32 + g * 8);
        bf16x8 Bf[4];
        #pragma unroll
        for (int vt = 0; vt < 4; ++vt)
            Bf[vt] = *(const bf16x8*)(&wt[cur][(vt * 16 + l15) * 40 + g * 8]);
        #pragma unroll
        for (int vt = 0; vt < 4; ++vt)
            acc[vt] = __builtin_amdgcn_mfma_f32_16x16x32_bf16(A, Bf[vt], acc[vt], 0, 0, 0);
        if (kk < 15) {
            ushort4 pa, pb;
            pa.x = f2bf(na.x); pa.y = f2bf(na.y); pa.z = f2bf(na.z); pa.w = f2bf(na.w);
            pb.x = f2bf(nb.x); pb.y = f2bf(nb.y); pb.z = f2bf(nb.z); pb.w = f2bf(nb.w);
            *(ushort4*)(&wt[nxt][dst0]) = pa;
            *(ushort4*)(&wt[nxt][dst1]) = pb;
        }
        __syncthreads();
    }

    const int rowBase = mblk * 64 + wid * 16;
    #pragma unroll
    for (int vt = 0; vt < 4; ++vt) {
        const int col = n0 + vt * 16 + l15;
        const float bias = bsrc[nloc + vt * 16 + l15];
        #pragma unroll
        for (int r = 0; r < 4; ++r) {
            const int row = rowBase + g * 4 + r;
            mv[row * TWO_D + col] = acc[vt][r] + bias;
        }
    }
}

// ---------------------------------------------------------------------------
// K_z (unchanged — packed zp write, proven)
// ---------------------------------------------------------------------------
__global__ __launch_bounds__(256) void k_z(
    const int* __restrict__ center_id, const int* __restrict__ context_ids,
    const float* __restrict__ prior_means_w, const float* __restrict__ prior_vars_w,
    const float* __restrict__ vocab_W, const float* __restrict__ vocab_b,
    const float* __restrict__ epsilon, const float* __restrict__ mv,
    ushort_t* __restrict__ zp, float* __restrict__ base)
{
    __shared__ float red[8];
    __shared__ int cids[C];
    const int b = blockIdx.x, tid = threadIdx.x;
    const int cid = center_id[b];
    if (tid < C) cids[tid] = context_ids[b * C + tid];
    __syncthreads();

    const int i = tid;
    const float mean = mv[b * TWO_D + i];
    const float a    = mv[b * TWO_D + D + i];
    const float var  = softplus_f(a);
    const float z    = mean + __expf(0.5f * var) * epsilon[i];

    {
        const int mt  = b >> 4;
        const int kkz = i >> 5;
        const int lz  = ((i >> 3) & 3) * 16 + (b & 15);
        zp[(mt * 8 + kkz) * 512 + lz * 8 + (i & 7)] = f2bf(z);
    }

    const float pm = prior_means_w[cid * D + i];
    const float pv = softplus_f(prior_vars_w[cid * D + i]);
    const float dm = pm - mean;
    float klt = var / pv + dm * dm / pv - 1.f + __logf(pv) - __logf(var);

    float wsum = 0.f;
    #pragma unroll
    for (int c = 0; c < C; ++c) wsum += vocab_W[cids[c] * D + i];
    float p = z * wsum;

    klt = wave_reduce(klt);
    p = wave_reduce(p);
    const int wid = tid >> 6, lane = tid & 63;
    if (lane == 0) { red[wid] = klt; red[4 + wid] = p; }
    __syncthreads();
    if (tid == 0) {
        const float kl = 0.5f * (red[0] + red[1] + red[2] + red[3]);
        float cs = red[4] + red[5] + red[6] + red[7];
        #pragma unroll
        for (int c = 0; c < C; ++c) cs += vocab_b[cids[c]];
        base[b] = cs - kl;
    }
}

// ---------------------------------------------------------------------------
// K3 (v10): FULLY COALESCED VMEM.
// Grid 782 x 256 thr (4 waves). Tile: 64 vocab rows (contiguous 64 KB).
// Staging: 16 wave-instructions, EACH = one full 1KB vocab row (lane*16B
//   linear). sched_barrier fence forces all 16 loads in flight (v4 fix).
//   cvt f32->bf16, ds_write to XOR-swizzled LDS (write: wave-uniform row ->
//   conflict-free; read: rows spread over all banks, 2-way = free).
// One __syncthreads. Then 8 K-steps, ZERO barriers: B via swizzled
//   ds_read_b128, A from packed zp (coalesced 1KB chunks, L2-hot).
// Epilogue: exp + 16-lane reduce, contiguous partial stores.
// ---------------------------------------------------------------------------
__global__ __launch_bounds__(256, 4) void k3_logits(
    const float* __restrict__ vocab_W, const float* __restrict__ vocab_b,
    const ushort_t* __restrict__ zp, float* __restrict__ partial)
{
    __shared__ __align__(16) ushort_t ldsB[64 * 256];   // 32 KB

    const int tid = threadIdx.x;
    const int blk = blockIdx.x;              // 0..781
    const int v0 = blk * VBLK;
    const int wid = tid >> 6, lane = tid & 63;
    const int l15 = lane & 15, g = lane >> 4;

    // ---- bias first (joins FIFO head; drained by __syncthreads anyway)
    float bias[4];
    bool vld[4];
    #pragma unroll
    for (int vt = 0; vt < 4; ++vt) {
        const int v = v0 + vt * 16 + l15;
        vld[vt] = (v < V);
        bias[vt] = vocab_b[min(v, V - 1)];
    }

    // ---- stage: 16 fully-coalesced rounds; round j, wave w = row j*4+w.
    f32x4 st[16];
    const int maxidx = V * D - 4;
    #pragma unroll
    for (int j = 0; j < 16; ++j) {
        int idx = v0 * D + j * 4096 + tid * 4;           // 4096 floats = 16KB/4
        idx = min(idx, maxidx);                          // clamp (last block)
        st[j] = *(const f32x4*)(vocab_W + idx);
    }
    __builtin_amdgcn_sched_barrier(0);                    // all 16 in flight

    #pragma unroll
    for (int j = 0; j < 16; ++j) {
        const int row = j * 4 + wid;                      // wave-uniform
        ushort4 p;
        p.x = f2bf(st[j][0]); p.y = f2bf(st[j][1]);
        p.z = f2bf(st[j][2]); p.w = f2bf(st[j][3]);
        // bf16 byte col = lane*8 -> ushort idx = lane*4, XOR-swizzled
        *(ushort4*)(ldsB + row * 256 + ((lane * 4) ^ ((row & 7) << 3))) = p;
    }
    __syncthreads();

    // ---- MFMA: 8 k-steps, no barriers. A: zp chunk (mt*8+kk), mt=wid*4+bt.
    f32x4 acc[4][4] = {};
    #pragma unroll 1
    for (int kk = 0; kk < 8; ++kk) {
        bf16x8 A[4], Bf[4];
        #pragma unroll
        for (int bt = 0; bt < 4; ++bt) {
            const int mt = wid * 4 + bt;
            A[bt] = *(const bf16x8*)(zp + ((mt * 8 + kk) << 9) + (lane << 3));
        }
        #pragma unroll
        for (int vt = 0; vt < 4; ++vt) {
            const int row = vt * 16 + l15;
            Bf[vt] = *(const bf16x8*)(
                ldsB + row * 256 + ((kk * 32 + g * 8) ^ ((row & 7) << 3)));
        }
        #pragma unroll
        for (int bt = 0; bt < 4; ++bt)
            #pragma unroll
            for (int vt = 0; vt < 4; ++vt)
                acc[bt][vt] = __builtin_amdgcn_mfma_f32_16x16x32_bf16(
                    A[bt], Bf[vt], acc[bt][vt], 0, 0, 0);
    }

    // ---- epilogue: per (blk, vt) partial over 16 valid v's, per b-row
    #pragma unroll
    for (int vt = 0; vt < 4; ++vt) {
        #pragma unroll
        for (int bt = 0; bt < 4; ++bt) {
            #pragma unroll
            for (int r = 0; r < 4; ++r) {
                float s = vld[vt] ? __expf(acc[bt][vt][r] + bias[vt]) : 0.f;
                s += __shfl_xor(s, 1); s += __shfl_xor(s, 2);
                s += __shfl_xor(s, 4); s += __shfl_xor(s, 8);
                if (l15 == 0) {
                    const int brow = wid * 64 + bt * 16 + g * 4 + r;
                    partial[(blk * 4 + vt) * 256 + brow] = s;
                }
            }
        }
    }
}

// ---------------------------------------------------------------------------
// K4: partial is [PCOLS][256]; 16 blocks, each owns 16 b's (coalesced).
// ---------------------------------------------------------------------------
__global__ __launch_bounds__(256) void k4_lse(
    const float* __restrict__ partial, const float* __restrict__ base,
    float* __restrict__ outb)
{
    __shared__ float red[64];
    const int beta = blockIdx.x;
    const int tid = threadIdx.x;
    const int b = beta * 16 + (tid & 15);
    float s = 0.f;
    for (int i = tid >> 4; i < PCOLS; i += 16)
        s += partial[i * 256 + b];
    s += __shfl_xor(s, 16);
    s += __shfl_xor(s, 32);
    const int wid = tid >> 6, lane = tid & 63;
    if (lane < 16) red[wid * 16 + lane] = s;
    __syncthreads();
    if (tid < 16) {
        const float tot = red[tid] + red[16 + tid] + red[32 + tid] + red[48 + tid];
        outb[beta * 16 + tid] = base[beta * 16 + tid] - (float)C * __logf(tot);
    }
}

// ---------------------------------------------------------------------------
// K5 (unchanged, proven)
// ---------------------------------------------------------------------------
__global__ __launch_bounds__(256) void k5_final(
    const float* __restrict__ outb, float* __restrict__ out)
{
    __shared__ float red[4];
    const int tid = threadIdx.x;
    float s = outb[tid];
    s = wave_reduce(s);
    if ((tid & 63) == 0) red[tid >> 6] = s;
    __syncthreads();
    if (tid == 0) out[0] = red[0] + red[1] + red[2] + red[3];
}

extern "C" void kernel_launch(void* const* d_in, const int* in_sizes, int n_in,
                              void* d_out, int out_size, void* d_ws, size_t ws_size,
                              hipStream_t stream)
{
    const int*   center_id     = (const int*)d_in[0];
    const int*   context_ids   = (const int*)d_in[1];
    const float* embeddings    = (const float*)d_in[2];
    const float* prior_means_w = (const float*)d_in[3];
    const float* prior_vars_w  = (const float*)d_in[4];
    const float* enc_W         = (const float*)d_in[5];
    const float* enc_b         = (const float*)d_in[6];
    const float* mean_W        = (const float*)d_in[7];
    const float* mean_b        = (const float*)d_in[8];
    const float* var_W         = (const float*)d_in[9];
    const float* var_b         = (const float*)d_in[10];
    const float* vocab_W       = (const float*)d_in[11];
    const float* vocab_b       = (const float*)d_in[12];
    const float* epsilon       = (const float*)d_in[13];

    char* ws = (char*)d_ws;
    ushort_t* xbf     = (ushort_t*)ws;  ws += (size_t)MPAD * TWO_D * 2;   // 4 MB
    ushort_t* h_bf    = (ushort_t*)ws;  ws += (size_t)B * TWO_D * 2;      // 256 KB
    float*    mv      = (float*)ws;     ws += (size_t)B * TWO_D * 4;      // 512 KB
    ushort_t* zp      = (ushort_t*)ws;  ws += (size_t)B * D * 2;          // 128 KB
    float*    base    = (float*)ws;     ws += B * 4;
    float*    outb    = (float*)ws;     ws += B * 4;
    float*    partial = (float*)ws;                                       // 3.2 MB

    hipLaunchKernelGGL(k0_gather, dim3(2048), dim3(256), 0, stream,
                       center_id, context_ids, embeddings, xbf);
    hipLaunchKernelGGL(k_enc, dim3(512), dim3(256), 0, stream,
                       enc_W, enc_b, xbf, h_bf);
    hipLaunchKernelGGL(k_heads, dim3(32), dim3(256), 0, stream,
                       mean_W, mean_b, var_W, var_b, h_bf, mv);
    hipLaunchKernelGGL(k_z, dim3(B), dim3(256), 0, stream,
                       center_id, context_ids, prior_means_w, prior_vars_w,
                       vocab_W, vocab_b, epsilon, mv, zp, base);
    hipLaunchKernelGGL(k3_logits, dim3(NBLK), dim3(256), 0, stream,
                       vocab_W, vocab_b, zp, partial);
    hipLaunchKernelGGL(k4_lse, dim3(16), dim3(256), 0, stream, partial, base, outb);
    hipLaunchKernelGGL(k5_final, dim3(1), dim3(256), 0, stream, outb, (float*)d_out);
}

// Round 12
// 80.732 us; speedup vs baseline: 2.2011x; 1.5655x over previous
//
#include <hip/hip_runtime.h>
#include <hip/hip_bf16.h>

// Sizes fixed by the reference
#define V 50000
#define D 256
#define B 256
#define C 10
#define TWO_D 512
#define VBLK 64
#define NBLK ((V + VBLK - 1) / VBLK)   // 782
#define PCOLS (NBLK * 4)               // 3128 partial columns (blk, vt)
#define MPAD 4096                      // 256 b * 16 (c padded 10 -> 16)

typedef __bf16 bf16x8 __attribute__((ext_vector_type(8)));
typedef float f32x4 __attribute__((ext_vector_type(4)));
typedef unsigned short ushort_t;
typedef unsigned int uint_t;

__device__ inline ushort_t f2bf(float f) {
    uint_t u = __builtin_bit_cast(uint_t, f);
    uint_t r = (u + 0x7FFFu + ((u >> 16) & 1u)) >> 16;
    return (ushort_t)r;
}

__device__ inline float softplus_f(float x) {
    return (x > 0.f) ? (x + log1pf(__expf(-x))) : log1pf(__expf(x));
}

__device__ inline float wave_reduce(float v) {
    #pragma unroll
    for (int m = 1; m < 64; m <<= 1) v += __shfl_xor(v, m);
    return v;
}

// ---------------------------------------------------------------------------
// K0 (unchanged, proven)
// ---------------------------------------------------------------------------
__global__ __launch_bounds__(256) void k0_gather(
    const int* __restrict__ center_id, const int* __restrict__ context_ids,
    const float* __restrict__ embeddings, ushort_t* __restrict__ xbf)
{
    const int idx = blockIdx.x * 256 + threadIdx.x;
    const int m = idx >> 7;
    const int q = idx & 127;
    const int k = q * 4;
    const int b = m >> 4, c = m & 15;
    ushort4 o;
    if (k < D) {
        const float4 v = *(const float4*)(embeddings + center_id[b] * D + k);
        o.x = f2bf(v.x); o.y = f2bf(v.y); o.z = f2bf(v.z); o.w = f2bf(v.w);
    } else if (c < C) {
        const float4 v = *(const float4*)(embeddings + context_ids[b * C + c] * D + (k - D));
        o.x = f2bf(v.x); o.y = f2bf(v.y); o.z = f2bf(v.z); o.w = f2bf(v.w);
    } else {
        o.x = 0; o.y = 0; o.z = 0; o.w = 0;
    }
    *(ushort4*)(xbf + idx * 4) = o;
}

// ---------------------------------------------------------------------------
// K_enc (unchanged, proven)
// ---------------------------------------------------------------------------
__global__ __launch_bounds__(256) void k_enc(
    const float* __restrict__ enc_W, const float* __restrict__ enc_b,
    const ushort_t* __restrict__ xbf, ushort_t* __restrict__ h_bf)
{
    __shared__ __align__(16) ushort_t wt[2][64 * 40];
    const int tid = threadIdx.x;
    const int mblk = blockIdx.x & 63;
    const int nblk = blockIdx.x >> 6;
    const int n0 = nblk * 64;
    const int wid = tid >> 6, lane = tid & 63;
    const int l15 = lane & 15, g = lane >> 4;

    const int r0 = tid >> 3, kq = tid & 7, r1 = r0 + 32;
    const float* src0 = enc_W + (n0 + r0) * TWO_D + kq * 4;
    const float* src1 = enc_W + (n0 + r1) * TWO_D + kq * 4;
    const int dst0 = r0 * 40 + kq * 4;
    const int dst1 = r1 * 40 + kq * 4;

    {
        const float4 na = *(const float4*)(src0);
        const float4 nb = *(const float4*)(src1);
        ushort4 pa, pb;
        pa.x = f2bf(na.x); pa.y = f2bf(na.y); pa.z = f2bf(na.z); pa.w = f2bf(na.w);
        pb.x = f2bf(nb.x); pb.y = f2bf(nb.y); pb.z = f2bf(nb.z); pb.w = f2bf(nb.w);
        *(ushort4*)(&wt[0][dst0]) = pa;
        *(ushort4*)(&wt[0][dst1]) = pb;
    }
    __syncthreads();

    const int rowA = mblk * 64 + wid * 16 + l15;
    f32x4 acc[4] = {};
    #pragma unroll 1
    for (int kk = 0; kk < 16; ++kk) {
        const int cur = kk & 1, nxt = cur ^ 1;
        float4 na, nb;
        if (kk < 15) {
            na = *(const float4*)(src0 + (kk + 1) * 32);
            nb = *(const float4*)(src1 + (kk + 1) * 32);
        }
        const bf16x8 A = *(const bf16x8*)(xbf + rowA * TWO_D + kk * 32 + g * 8);
        bf16x8 Bf[4];
        #pragma unroll
        for (int vt = 0; vt < 4; ++vt)
            Bf[vt] = *(const bf16x8*)(&wt[cur][(vt * 16 + l15) * 40 + g * 8]);
        #pragma unroll
        for (int vt = 0; vt < 4; ++vt)
            acc[vt] = __builtin_amdgcn_mfma_f32_16x16x32_bf16(A, Bf[vt], acc[vt], 0, 0, 0);
        if (kk < 15) {
            ushort4 pa, pb;
            pa.x = f2bf(na.x); pa.y = f2bf(na.y); pa.z = f2bf(na.z); pa.w = f2bf(na.w);
            pb.x = f2bf(nb.x); pb.y = f2bf(nb.y); pb.z = f2bf(nb.z); pb.w = f2bf(nb.w);
            *(ushort4*)(&wt[nxt][dst0]) = pa;
            *(ushort4*)(&wt[nxt][dst1]) = pb;
        }
        __syncthreads();
    }

    const int b = mblk * 4 + wid;
    #pragma unroll
    for (int vt = 0; vt < 4; ++vt) {
        const int j = n0 + vt * 16 + l15;
        const float bias = enc_b[j];
        float s = 0.f;
        #pragma unroll
        for (int r = 0; r < 4; ++r) {
            const int c = g * 4 + r;
            const float vv = acc[vt][r] + bias;
            s += (c < C) ? fmaxf(vv, 0.f) : 0.f;
        }
        s += __shfl_xor(s, 16);
        s += __shfl_xor(s, 32);
        if (g == 0) h_bf[b * TWO_D + j] = f2bf(s);
    }
}

// ---------------------------------------------------------------------------
// K_heads (unchanged, proven)
// ---------------------------------------------------------------------------
__global__ __launch_bounds__(256) void k_heads(
    const float* __restrict__ mean_W, const float* __restrict__ mean_b,
    const float* __restrict__ var_W, const float* __restrict__ var_b,
    const ushort_t* __restrict__ h_bf, float* __restrict__ mv)
{
    __shared__ __align__(16) ushort_t wt[2][64 * 40];
    const int tid = threadIdx.x;
    const int mblk = blockIdx.x & 3;
    const int nblk = blockIdx.x >> 2;
    const int n0 = nblk * 64;
    const float* Wsrc = (nblk < 4) ? mean_W : var_W;
    const float* bsrc = (nblk < 4) ? mean_b : var_b;
    const int nloc = (nblk & 3) * 64;
    const int wid = tid >> 6, lane = tid & 63;
    const int l15 = lane & 15, g = lane >> 4;

    const int r0 = tid >> 3, kq = tid & 7, r1 = r0 + 32;
    const float* src0 = Wsrc + (nloc + r0) * TWO_D + kq * 4;
    const float* src1 = Wsrc + (nloc + r1) * TWO_D + kq * 4;
    const int dst0 = r0 * 40 + kq * 4;
    const int dst1 = r1 * 40 + kq * 4;

    {
        const float4 na = *(const float4*)(src0);
        const float4 nb = *(const float4*)(src1);
        ushort4 pa, pb;
        pa.x = f2bf(na.x); pa.y = f2bf(na.y); pa.z = f2bf(na.z); pa.w = f2bf(na.w);
        pb.x = f2bf(nb.x); pb.y = f2bf(nb.y); pb.z = f2bf(nb.z); pb.w = f2bf(nb.w);
        *(ushort4*)(&wt[0][dst0]) = pa;
        *(ushort4*)(&wt[0][dst1]) = pb;
    }
    __syncthreads();

    const int rowA = mblk * 64 + wid * 16 + l15;
    f32x4 acc[4] = {};
    #pragma unroll 1
    for (int kk = 0; kk < 16; ++kk) {
        const int cur = kk & 1, nxt = cur ^ 1;
        float4 na, nb;
        if (kk < 15) {
            na = *(const float4*)(src0 + (kk + 1) * 32);
            nb = *(const float4*)(src1 + (kk + 1) * 32);
        }
        const bf16x8 A = *(const bf16x8*)(h_bf + rowA * TWO_D + kk * 32 + g * 8);
        bf16x8 Bf[4];
        #pragma unroll
        for (int vt = 0; vt < 4; ++vt)
            Bf[vt] = *(const bf16x8*)(&wt[cur][(vt * 16 + l15) * 40 + g * 8]);
        #pragma unroll
        for (int vt = 0; vt < 4; ++vt)
            acc[vt] = __builtin_amdgcn_mfma_f32_16x16x32_bf16(A, Bf[vt], acc[vt], 0, 0, 0);
        if (kk < 15) {
            ushort4 pa, pb;
            pa.x = f2bf(na.x); pa.y = f2bf(na.y); pa.z = f2bf(na.z); pa.w = f2bf(na.w);
            pb.x = f2bf(nb.x); pb.y = f2bf(nb.y); pb.z = f2bf(nb.z); pb.w = f2bf(nb.w);
            *(ushort4*)(&wt[nxt][dst0]) = pa;
            *(ushort4*)(&wt[nxt][dst1]) = pb;
        }
        __syncthreads();
    }

    const int rowBase = mblk * 64 + wid * 16;
    #pragma unroll
    for (int vt = 0; vt < 4; ++vt) {
        const int col = n0 + vt * 16 + l15;
        const float bias = bsrc[nloc + vt * 16 + l15];
        #pragma unroll
        for (int r = 0; r < 4; ++r) {
            const int row = rowBase + g * 4 + r;
            mv[row * TWO_D + col] = acc[vt][r] + bias;
        }
    }
}

// ---------------------------------------------------------------------------
// K_z (unchanged — packed zp write, proven)
// ---------------------------------------------------------------------------
__global__ __launch_bounds__(256) void k_z(
    const int* __restrict__ center_id, const int* __restrict__ context_ids,
    const float* __restrict__ prior_means_w, const float* __restrict__ prior_vars_w,
    const float* __restrict__ vocab_W, const float* __restrict__ vocab_b,
    const float* __restrict__ epsilon, const float* __restrict__ mv,
    ushort_t* __restrict__ zp, float* __restrict__ base)
{
    __shared__ float red[8];
    __shared__ int cids[C];
    const int b = blockIdx.x, tid = threadIdx.x;
    const int cid = center_id[b];
    if (tid < C) cids[tid] = context_ids[b * C + tid];
    __syncthreads();

    const int i = tid;
    const float mean = mv[b * TWO_D + i];
    const float a    = mv[b * TWO_D + D + i];
    const float var  = softplus_f(a);
    const float z    = mean + __expf(0.5f * var) * epsilon[i];

    {
        const int mt  = b >> 4;
        const int kkz = i >> 5;
        const int lz  = ((i >> 3) & 3) * 16 + (b & 15);
        zp[(mt * 8 + kkz) * 512 + lz * 8 + (i & 7)] = f2bf(z);
    }

    const float pm = prior_means_w[cid * D + i];
    const float pv = softplus_f(prior_vars_w[cid * D + i]);
    const float dm = pm - mean;
    float klt = var / pv + dm * dm / pv - 1.f + __logf(pv) - __logf(var);

    float wsum = 0.f;
    #pragma unroll
    for (int c = 0; c < C; ++c) wsum += vocab_W[cids[c] * D + i];
    float p = z * wsum;

    klt = wave_reduce(klt);
    p = wave_reduce(p);
    const int wid = tid >> 6, lane = tid & 63;
    if (lane == 0) { red[wid] = klt; red[4 + wid] = p; }
    __syncthreads();
    if (tid == 0) {
        const float kl = 0.5f * (red[0] + red[1] + red[2] + red[3]);
        float cs = red[4] + red[5] + red[6] + red[7];
        #pragma unroll
        for (int c = 0; c < C; ++c) cs += vocab_b[cids[c]];
        base[b] = cs - kl;
    }
}

// ---------------------------------------------------------------------------
// K3 (v10 core, b-major partial store): FULLY COALESCED VMEM.
// Grid 782 x 256 thr. Staging: 16 wave-instructions, each one full 1KB row.
// XOR-swizzled LDS; one __syncthreads; 8 barrier-free K-steps.
// Only change vs round 11: partial store index is b-major (scattered 4B,
// proven cheap rounds 1-8) so k4 can read contiguously.
// ---------------------------------------------------------------------------
__global__ __launch_bounds__(256, 4) void k3_logits(
    const float* __restrict__ vocab_W, const float* __restrict__ vocab_b,
    const ushort_t* __restrict__ zp, float* __restrict__ partial)
{
    __shared__ __align__(16) ushort_t ldsB[64 * 256];   // 32 KB

    const int tid = threadIdx.x;
    const int blk = blockIdx.x;              // 0..781
    const int v0 = blk * VBLK;
    const int wid = tid >> 6, lane = tid & 63;
    const int l15 = lane & 15, g = lane >> 4;

    float bias[4];
    bool vld[4];
    #pragma unroll
    for (int vt = 0; vt < 4; ++vt) {
        const int v = v0 + vt * 16 + l15;
        vld[vt] = (v < V);
        bias[vt] = vocab_b[min(v, V - 1)];
    }

    // ---- stage: 16 fully-coalesced rounds; round j, wave w = row j*4+w.
    f32x4 st[16];
    const int maxidx = V * D - 4;
    #pragma unroll
    for (int j = 0; j < 16; ++j) {
        int idx = v0 * D + j * 4096 + tid * 4;
        idx = min(idx, maxidx);
        st[j] = *(const f32x4*)(vocab_W + idx);
    }
    __builtin_amdgcn_sched_barrier(0);

    #pragma unroll
    for (int j = 0; j < 16; ++j) {
        const int row = j * 4 + wid;
        ushort4 p;
        p.x = f2bf(st[j][0]); p.y = f2bf(st[j][1]);
        p.z = f2bf(st[j][2]); p.w = f2bf(st[j][3]);
        *(ushort4*)(ldsB + row * 256 + ((lane * 4) ^ ((row & 7) << 3))) = p;
    }
    __syncthreads();

    // ---- MFMA: 8 k-steps, no barriers.
    f32x4 acc[4][4] = {};
    #pragma unroll 1
    for (int kk = 0; kk < 8; ++kk) {
        bf16x8 A[4], Bf[4];
        #pragma unroll
        for (int bt = 0; bt < 4; ++bt) {
            const int mt = wid * 4 + bt;
            A[bt] = *(const bf16x8*)(zp + ((mt * 8 + kk) << 9) + (lane << 3));
        }
        #pragma unroll
        for (int vt = 0; vt < 4; ++vt) {
            const int row = vt * 16 + l15;
            Bf[vt] = *(const bf16x8*)(
                ldsB + row * 256 + ((kk * 32 + g * 8) ^ ((row & 7) << 3)));
        }
        #pragma unroll
        for (int bt = 0; bt < 4; ++bt)
            #pragma unroll
            for (int vt = 0; vt < 4; ++vt)
                acc[bt][vt] = __builtin_amdgcn_mfma_f32_16x16x32_bf16(
                    A[bt], Bf[vt], acc[bt][vt], 0, 0, 0);
    }

    // ---- epilogue: b-major partial store (4B scattered, write-combines
    //      within the 16B (blk*4+vt) quad per brow)
    #pragma unroll
    for (int vt = 0; vt < 4; ++vt) {
        #pragma unroll
        for (int bt = 0; bt < 4; ++bt) {
            #pragma unroll
            for (int r = 0; r < 4; ++r) {
                float s = vld[vt] ? __expf(acc[bt][vt][r] + bias[vt]) : 0.f;
                s += __shfl_xor(s, 1); s += __shfl_xor(s, 2);
                s += __shfl_xor(s, 4); s += __shfl_xor(s, 8);
                if (l15 == 0) {
                    const int brow = wid * 64 + bt * 16 + g * 4 + r;
                    partial[brow * PCOLS + blk * 4 + vt] = s;
                }
            }
        }
    }
}

// ---------------------------------------------------------------------------
// PROBE: k3_stream — pure float4 grid-stride read of all vocab_W (51.2 MB).
// The streaming ceiling for this buffer in this context.
// ---------------------------------------------------------------------------
__global__ __launch_bounds__(256) void k3_stream(
    const float* __restrict__ vocab_W, float* __restrict__ dummy)
{
    const int tid = blockIdx.x * 256 + threadIdx.x;
    const int stride = gridDim.x * 256;
    float s = 0.f;
    for (int i = tid; i < V * D / 4; i += stride) {
        const f32x4 v = ((const f32x4*)vocab_W)[i];
        s += v[0] + v[1] + v[2] + v[3];
    }
    s = wave_reduce(s);
    if ((threadIdx.x & 63) == 0)
        dummy[(blockIdx.x * 4) + (threadIdx.x >> 6)] = s;
}

// ---------------------------------------------------------------------------
// K4 (reverted to proven round-1-7 shape): 256 blocks, one per b;
// contiguous 3128-float row sum -> coalesced, massively parallel.
// ---------------------------------------------------------------------------
__global__ __launch_bounds__(256) void k4_lse(
    const float* __restrict__ partial, const float* __restrict__ base,
    float* __restrict__ outb)
{
    __shared__ float red[4];
    const int b = blockIdx.x, tid = threadIdx.x;
    float s = 0.f;
    for (int i = tid; i < PCOLS; i += 256) s += partial[b * PCOLS + i];
    s = wave_reduce(s);
    if ((tid & 63) == 0) red[tid >> 6] = s;
    __syncthreads();
    if (tid == 0) {
        const float tot = red[0] + red[1] + red[2] + red[3];
        outb[b] = base[b] - (float)C * __logf(tot);
    }
}

// ---------------------------------------------------------------------------
// K5 (unchanged, proven)
// ---------------------------------------------------------------------------
__global__ __launch_bounds__(256) void k5_final(
    const float* __restrict__ outb, float* __restrict__ out)
{
    __shared__ float red[4];
    const int tid = threadIdx.x;
    float s = outb[tid];
    s = wave_reduce(s);
    if ((tid & 63) == 0) red[tid >> 6] = s;
    __syncthreads();
    if (tid == 0) out[0] = red[0] + red[1] + red[2] + red[3];
}

extern "C" void kernel_launch(void* const* d_in, const int* in_sizes, int n_in,
                              void* d_out, int out_size, void* d_ws, size_t ws_size,
                              hipStream_t stream)
{
    const int*   center_id     = (const int*)d_in[0];
    const int*   context_ids   = (const int*)d_in[1];
    const float* embeddings    = (const float*)d_in[2];
    const float* prior_means_w = (const float*)d_in[3];
    const float* prior_vars_w  = (const float*)d_in[4];
    const float* enc_W         = (const float*)d_in[5];
    const float* enc_b         = (const float*)d_in[6];
    const float* mean_W        = (const float*)d_in[7];
    const float* mean_b        = (const float*)d_in[8];
    const float* var_W         = (const float*)d_in[9];
    const float* var_b         = (const float*)d_in[10];
    const float* vocab_W       = (const float*)d_in[11];
    const float* vocab_b       = (const float*)d_in[12];
    const float* epsilon       = (const float*)d_in[13];

    char* ws = (char*)d_ws;
    ushort_t* xbf     = (ushort_t*)ws;  ws += (size_t)MPAD * TWO_D * 2;   // 4 MB
    ushort_t* h_bf    = (ushort_t*)ws;  ws += (size_t)B * TWO_D * 2;      // 256 KB
    float*    mv      = (float*)ws;     ws += (size_t)B * TWO_D * 4;      // 512 KB
    ushort_t* zp      = (ushort_t*)ws;  ws += (size_t)B * D * 2;          // 128 KB
    float*    base    = (float*)ws;     ws += B * 4;
    float*    outb    = (float*)ws;     ws += B * 4;
    float*    partial = (float*)ws;     ws += (size_t)B * PCOLS * 4;      // 3.2 MB
    float*    dummy   = (float*)ws;                                       // probe sink

    hipLaunchKernelGGL(k0_gather, dim3(2048), dim3(256), 0, stream,
                       center_id, context_ids, embeddings, xbf);
    hipLaunchKernelGGL(k_enc, dim3(512), dim3(256), 0, stream,
                       enc_W, enc_b, xbf, h_bf);
    hipLaunchKernelGGL(k_heads, dim3(32), dim3(256), 0, stream,
                       mean_W, mean_b, var_W, var_b, h_bf, mv);
    hipLaunchKernelGGL(k_z, dim3(B), dim3(256), 0, stream,
                       center_id, context_ids, prior_means_w, prior_vars_w,
                       vocab_W, vocab_b, epsilon, mv, zp, base);
    hipLaunchKernelGGL(k3_logits, dim3(NBLK), dim3(256), 0, stream,
                       vocab_W, vocab_b, zp, partial);
    // --- diagnostic probe (output discarded) ---
    hipLaunchKernelGGL(k3_stream, dim3(1024), dim3(256), 0, stream,
                       vocab_W, dummy);
    // --- end probe ---
    hipLaunchKernelGGL(k4_lse, dim3(B), dim3(256), 0, stream, partial, base, outb);
    hipLaunchKernelGGL(k5_final, dim3(1), dim3(256), 0, stream, outb, (float*)d_out);
}

// Round 13
// 70.698 us; speedup vs baseline: 2.5134x; 1.1419x over previous
//
#include <hip/hip_runtime.h>
#include <hip/hip_bf16.h>

// Sizes fixed by the reference
#define V 50000
#define D 256
#define B 256
#define C 10
#define TWO_D 512
#define VBLK 64
#define NBLK ((V + VBLK - 1) / VBLK)   // 782
#define VPAD (NBLK * VBLK)             // 50048
#define QV (VPAD / 4)                  // 12512
#define MPAD 4096                      // 256 b * 16 (c padded 10 -> 16)

typedef __bf16 bf16x8 __attribute__((ext_vector_type(8)));
typedef float f32x4 __attribute__((ext_vector_type(4)));
typedef unsigned short ushort_t;
typedef unsigned int uint_t;

__device__ inline ushort_t f2bf(float f) {
    uint_t u = __builtin_bit_cast(uint_t, f);
    uint_t r = (u + 0x7FFFu + ((u >> 16) & 1u)) >> 16;
    return (ushort_t)r;
}

__device__ inline float bf2f(ushort_t u) {
    return __builtin_bit_cast(float, (uint_t)u << 16);
}

__device__ inline float softplus_f(float x) {
    return (x > 0.f) ? (x + log1pf(__expf(-x))) : log1pf(__expf(x));
}

__device__ inline float wave_reduce(float v) {
    #pragma unroll
    for (int m = 1; m < 64; m <<= 1) v += __shfl_xor(v, m);
    return v;
}

// ---------------------------------------------------------------------------
// K0 (unchanged, proven)
// ---------------------------------------------------------------------------
__global__ __launch_bounds__(256) void k0_gather(
    const int* __restrict__ center_id, const int* __restrict__ context_ids,
    const float* __restrict__ embeddings, ushort_t* __restrict__ xbf)
{
    const int idx = blockIdx.x * 256 + threadIdx.x;
    const int m = idx >> 7;
    const int q = idx & 127;
    const int k = q * 4;
    const int b = m >> 4, c = m & 15;
    ushort4 o;
    if (k < D) {
        const float4 v = *(const float4*)(embeddings + center_id[b] * D + k);
        o.x = f2bf(v.x); o.y = f2bf(v.y); o.z = f2bf(v.z); o.w = f2bf(v.w);
    } else if (c < C) {
        const float4 v = *(const float4*)(embeddings + context_ids[b * C + c] * D + (k - D));
        o.x = f2bf(v.x); o.y = f2bf(v.y); o.z = f2bf(v.z); o.w = f2bf(v.w);
    } else {
        o.x = 0; o.y = 0; o.z = 0; o.w = 0;
    }
    *(ushort4*)(xbf + idx * 4) = o;
}

// ---------------------------------------------------------------------------
// K_enc (unchanged, proven)
// ---------------------------------------------------------------------------
__global__ __launch_bounds__(256) void k_enc(
    const float* __restrict__ enc_W, const float* __restrict__ enc_b,
    const ushort_t* __restrict__ xbf, ushort_t* __restrict__ h_bf)
{
    __shared__ __align__(16) ushort_t wt[2][64 * 40];
    const int tid = threadIdx.x;
    const int mblk = blockIdx.x & 63;
    const int nblk = blockIdx.x >> 6;
    const int n0 = nblk * 64;
    const int wid = tid >> 6, lane = tid & 63;
    const int l15 = lane & 15, g = lane >> 4;

    const int r0 = tid >> 3, kq = tid & 7, r1 = r0 + 32;
    const float* src0 = enc_W + (n0 + r0) * TWO_D + kq * 4;
    const float* src1 = enc_W + (n0 + r1) * TWO_D + kq * 4;
    const int dst0 = r0 * 40 + kq * 4;
    const int dst1 = r1 * 40 + kq * 4;

    {
        const float4 na = *(const float4*)(src0);
        const float4 nb = *(const float4*)(src1);
        ushort4 pa, pb;
        pa.x = f2bf(na.x); pa.y = f2bf(na.y); pa.z = f2bf(na.z); pa.w = f2bf(na.w);
        pb.x = f2bf(nb.x); pb.y = f2bf(nb.y); pb.z = f2bf(nb.z); pb.w = f2bf(nb.w);
        *(ushort4*)(&wt[0][dst0]) = pa;
        *(ushort4*)(&wt[0][dst1]) = pb;
    }
    __syncthreads();

    const int rowA = mblk * 64 + wid * 16 + l15;
    f32x4 acc[4] = {};
    #pragma unroll 1
    for (int kk = 0; kk < 16; ++kk) {
        const int cur = kk & 1, nxt = cur ^ 1;
        float4 na, nb;
        if (kk < 15) {
            na = *(const float4*)(src0 + (kk + 1) * 32);
            nb = *(const float4*)(src1 + (kk + 1) * 32);
        }
        const bf16x8 A = *(const bf16x8*)(xbf + rowA * TWO_D + kk * 32 + g * 8);
        bf16x8 Bf[4];
        #pragma unroll
        for (int vt = 0; vt < 4; ++vt)
            Bf[vt] = *(const bf16x8*)(&wt[cur][(vt * 16 + l15) * 40 + g * 8]);
        #pragma unroll
        for (int vt = 0; vt < 4; ++vt)
            acc[vt] = __builtin_amdgcn_mfma_f32_16x16x32_bf16(A, Bf[vt], acc[vt], 0, 0, 0);
        if (kk < 15) {
            ushort4 pa, pb;
            pa.x = f2bf(na.x); pa.y = f2bf(na.y); pa.z = f2bf(na.z); pa.w = f2bf(na.w);
            pb.x = f2bf(nb.x); pb.y = f2bf(nb.y); pb.z = f2bf(nb.z); pb.w = f2bf(nb.w);
            *(ushort4*)(&wt[nxt][dst0]) = pa;
            *(ushort4*)(&wt[nxt][dst1]) = pb;
        }
        __syncthreads();
    }

    const int b = mblk * 4 + wid;
    #pragma unroll
    for (int vt = 0; vt < 4; ++vt) {
        const int j = n0 + vt * 16 + l15;
        const float bias = enc_b[j];
        float s = 0.f;
        #pragma unroll
        for (int r = 0; r < 4; ++r) {
            const int c = g * 4 + r;
            const float vv = acc[vt][r] + bias;
            s += (c < C) ? fmaxf(vv, 0.f) : 0.f;
        }
        s += __shfl_xor(s, 16);
        s += __shfl_xor(s, 32);
        if (g == 0) h_bf[b * TWO_D + j] = f2bf(s);
    }
}

// ---------------------------------------------------------------------------
// K_heads (unchanged, proven)
// ---------------------------------------------------------------------------
__global__ __launch_bounds__(256) void k_heads(
    const float* __restrict__ mean_W, const float* __restrict__ mean_b,
    const float* __restrict__ var_W, const float* __restrict__ var_b,
    const ushort_t* __restrict__ h_bf, float* __restrict__ mv)
{
    __shared__ __align__(16) ushort_t wt[2][64 * 40];
    const int tid = threadIdx.x;
    const int mblk = blockIdx.x & 3;
    const int nblk = blockIdx.x >> 2;
    const int n0 = nblk * 64;
    const float* Wsrc = (nblk < 4) ? mean_W : var_W;
    const float* bsrc = (nblk < 4) ? mean_b : var_b;
    const int nloc = (nblk & 3) * 64;
    const int wid = tid >> 6, lane = tid & 63;
    const int l15 = lane & 15, g = lane >> 4;

    const int r0 = tid >> 3, kq = tid & 7, r1 = r0 + 32;
    const float* src0 = Wsrc + (nloc + r0) * TWO_D + kq * 4;
    const float* src1 = Wsrc + (nloc + r1) * TWO_D + kq * 4;
    const int dst0 = r0 * 40 + kq * 4;
    const int dst1 = r1 * 40 + kq * 4;

    {
        const float4 na = *(const float4*)(src0);
        const float4 nb = *(const float4*)(src1);
        ushort4 pa, pb;
        pa.x = f2bf(na.x); pa.y = f2bf(na.y); pa.z = f2bf(na.z); pa.w = f2bf(na.w);
        pb.x = f2bf(nb.x); pb.y = f2bf(nb.y); pb.z = f2bf(nb.z); pb.w = f2bf(nb.w);
        *(ushort4*)(&wt[0][dst0]) = pa;
        *(ushort4*)(&wt[0][dst1]) = pb;
    }
    __syncthreads();

    const int rowA = mblk * 64 + wid * 16 + l15;
    f32x4 acc[4] = {};
    #pragma unroll 1
    for (int kk = 0; kk < 16; ++kk) {
        const int cur = kk & 1, nxt = cur ^ 1;
        float4 na, nb;
        if (kk < 15) {
            na = *(const float4*)(src0 + (kk + 1) * 32);
            nb = *(const float4*)(src1 + (kk + 1) * 32);
        }
        const bf16x8 A = *(const bf16x8*)(h_bf + rowA * TWO_D + kk * 32 + g * 8);
        bf16x8 Bf[4];
        #pragma unroll
        for (int vt = 0; vt < 4; ++vt)
            Bf[vt] = *(const bf16x8*)(&wt[cur][(vt * 16 + l15) * 40 + g * 8]);
        #pragma unroll
        for (int vt = 0; vt < 4; ++vt)
            acc[vt] = __builtin_amdgcn_mfma_f32_16x16x32_bf16(A, Bf[vt], acc[vt], 0, 0, 0);
        if (kk < 15) {
            ushort4 pa, pb;
            pa.x = f2bf(na.x); pa.y = f2bf(na.y); pa.z = f2bf(na.z); pa.w = f2bf(na.w);
            pb.x = f2bf(nb.x); pb.y = f2bf(nb.y); pb.z = f2bf(nb.z); pb.w = f2bf(nb.w);
            *(ushort4*)(&wt[nxt][dst0]) = pa;
            *(ushort4*)(&wt[nxt][dst1]) = pb;
        }
        __syncthreads();
    }

    const int rowBase = mblk * 64 + wid * 16;
    #pragma unroll
    for (int vt = 0; vt < 4; ++vt) {
        const int col = n0 + vt * 16 + l15;
        const float bias = bsrc[nloc + vt * 16 + l15];
        #pragma unroll
        for (int r = 0; r < 4; ++r) {
            const int row = rowBase + g * 4 + r;
            mv[row * TWO_D + col] = acc[vt][r] + bias;
        }
    }
}

// ---------------------------------------------------------------------------
// K_z (unchanged — packed zp write, proven)
// ---------------------------------------------------------------------------
__global__ __launch_bounds__(256) void k_z(
    const int* __restrict__ center_id, const int* __restrict__ context_ids,
    const float* __restrict__ prior_means_w, const float* __restrict__ prior_vars_w,
    const float* __restrict__ vocab_W, const float* __restrict__ vocab_b,
    const float* __restrict__ epsilon, const float* __restrict__ mv,
    ushort_t* __restrict__ zp, float* __restrict__ base)
{
    __shared__ float red[8];
    __shared__ int cids[C];
    const int b = blockIdx.x, tid = threadIdx.x;
    const int cid = center_id[b];
    if (tid < C) cids[tid] = context_ids[b * C + tid];
    __syncthreads();

    const int i = tid;
    const float mean = mv[b * TWO_D + i];
    const float a    = mv[b * TWO_D + D + i];
    const float var  = softplus_f(a);
    const float z    = mean + __expf(0.5f * var) * epsilon[i];

    {
        const int mt  = b >> 4;
        const int kkz = i >> 5;
        const int lz  = ((i >> 3) & 3) * 16 + (b & 15);
        zp[(mt * 8 + kkz) * 512 + lz * 8 + (i & 7)] = f2bf(z);
    }

    const float pm = prior_means_w[cid * D + i];
    const float pv = softplus_f(prior_vars_w[cid * D + i]);
    const float dm = pm - mean;
    float klt = var / pv + dm * dm / pv - 1.f + __logf(pv) - __logf(var);

    float wsum = 0.f;
    #pragma unroll
    for (int c = 0; c < C; ++c) wsum += vocab_W[cids[c] * D + i];
    float p = z * wsum;

    klt = wave_reduce(klt);
    p = wave_reduce(p);
    const int wid = tid >> 6, lane = tid & 63;
    if (lane == 0) { red[wid] = klt; red[4 + wid] = p; }
    __syncthreads();
    if (tid == 0) {
        const float kl = 0.5f * (red[0] + red[1] + red[2] + red[3]);
        float cs = red[4] + red[5] + red[6] + red[7];
        #pragma unroll
        for (int c = 0; c < C; ++c) cs += vocab_b[cids[c]];
        base[b] = cs - kl;
    }
}

// ---------------------------------------------------------------------------
// K3a: PURE GEMM (round-12 staging+MFMA core unchanged; epilogue = plain
// bf16 stores of logits[b][v]). No exp, no shfl, no cross-lane, no
// cross-XCD write sharing (each block owns v-columns [v0, v0+64)).
// ---------------------------------------------------------------------------
__global__ __launch_bounds__(256, 4) void k3a_gemm(
    const float* __restrict__ vocab_W, const ushort_t* __restrict__ zp,
    ushort_t* __restrict__ logits)
{
    __shared__ __align__(16) ushort_t ldsB[64 * 256];   // 32 KB

    const int tid = threadIdx.x;
    const int blk = blockIdx.x;              // 0..781
    const int v0 = blk * VBLK;
    const int wid = tid >> 6, lane = tid & 63;
    const int l15 = lane & 15, g = lane >> 4;

    // ---- stage: 16 fully-coalesced rounds; round j, wave w = row j*4+w.
    f32x4 st[16];
    const int maxidx = V * D - 4;
    #pragma unroll
    for (int j = 0; j < 16; ++j) {
        int idx = v0 * D + j * 4096 + tid * 4;
        idx = min(idx, maxidx);
        st[j] = *(const f32x4*)(vocab_W + idx);
    }
    __builtin_amdgcn_sched_barrier(0);

    #pragma unroll
    for (int j = 0; j < 16; ++j) {
        const int row = j * 4 + wid;
        ushort4 p;
        p.x = f2bf(st[j][0]); p.y = f2bf(st[j][1]);
        p.z = f2bf(st[j][2]); p.w = f2bf(st[j][3]);
        *(ushort4*)(ldsB + row * 256 + ((lane * 4) ^ ((row & 7) << 3))) = p;
    }
    __syncthreads();

    // ---- MFMA: 8 k-steps, no barriers. A from packed zp (L2-hot).
    f32x4 acc[4][4] = {};
    #pragma unroll 1
    for (int kk = 0; kk < 8; ++kk) {
        bf16x8 A[4], Bf[4];
        #pragma unroll
        for (int bt = 0; bt < 4; ++bt) {
            const int mt = wid * 4 + bt;
            A[bt] = *(const bf16x8*)(zp + ((mt * 8 + kk) << 9) + (lane << 3));
        }
        #pragma unroll
        for (int vt = 0; vt < 4; ++vt) {
            const int row = vt * 16 + l15;
            Bf[vt] = *(const bf16x8*)(
                ldsB + row * 256 + ((kk * 32 + g * 8) ^ ((row & 7) << 3)));
        }
        #pragma unroll
        for (int bt = 0; bt < 4; ++bt)
            #pragma unroll
            for (int vt = 0; vt < 4; ++vt)
                acc[bt][vt] = __builtin_amdgcn_mfma_f32_16x16x32_bf16(
                    A[bt], Bf[vt], acc[bt][vt], 0, 0, 0);
    }

    // ---- epilogue: plain bf16 stores, logits[b][v] (fire-and-forget)
    #pragma unroll
    for (int bt = 0; bt < 4; ++bt)
        #pragma unroll
        for (int r = 0; r < 4; ++r) {
            const int brow = wid * 64 + bt * 16 + g * 4 + r;
            #pragma unroll
            for (int vt = 0; vt < 4; ++vt)
                logits[brow * VPAD + v0 + vt * 16 + l15] = f2bf(acc[bt][vt][r]);
        }
}

// ---------------------------------------------------------------------------
// K3b: PURE STREAM-REDUCE (k3_stream shape + exp). 1024 blocks x 256 thr.
// Block (b = bid>>2, q = bid&3) sums exp(logit+bias) over v in
// [q*QV, (q+1)*QV) for row b. Fully coalesced ushort4 + float4 loads.
// ---------------------------------------------------------------------------
__global__ __launch_bounds__(256) void k3b_expsum(
    const ushort_t* __restrict__ logits, const float* __restrict__ vocab_b,
    float* __restrict__ psum)
{
    __shared__ float red[4];
    const int b = blockIdx.x >> 2, q = blockIdx.x & 3;
    const int tid = threadIdx.x;
    const int vbase = q * QV;
    const ushort_t* src = logits + b * VPAD + vbase;
    float s = 0.f;
    for (int i = tid * 8; i < QV; i += 2048) {
        const ushort4 u0 = *(const ushort4*)(src + i);
        const ushort4 u1 = *(const ushort4*)(src + i + 4);
        const int v = vbase + i;
        if (v + 8 <= V) {
            const float4 b0 = *(const float4*)(vocab_b + v);
            const float4 b1 = *(const float4*)(vocab_b + v + 4);
            s += __expf(bf2f(u0.x) + b0.x) + __expf(bf2f(u0.y) + b0.y)
               + __expf(bf2f(u0.z) + b0.z) + __expf(bf2f(u0.w) + b0.w)
               + __expf(bf2f(u1.x) + b1.x) + __expf(bf2f(u1.y) + b1.y)
               + __expf(bf2f(u1.z) + b1.z) + __expf(bf2f(u1.w) + b1.w);
        } else {
            const ushort_t us[8] = {u0.x, u0.y, u0.z, u0.w, u1.x, u1.y, u1.z, u1.w};
            #pragma unroll
            for (int j = 0; j < 8; ++j) {
                const int vj = v + j;
                if (vj < V) s += __expf(bf2f(us[j]) + vocab_b[vj]);
            }
        }
    }
    s = wave_reduce(s);
    if ((tid & 63) == 0) red[tid >> 6] = s;
    __syncthreads();
    if (tid == 0) psum[blockIdx.x] = red[0] + red[1] + red[2] + red[3];
}

// ---------------------------------------------------------------------------
// K4: tiny — one block; per-b total = 4 quarter-sums; LSE.
// ---------------------------------------------------------------------------
__global__ __launch_bounds__(256) void k4_lse(
    const float* __restrict__ psum, const float* __restrict__ base,
    float* __restrict__ outb)
{
    const int b = threadIdx.x;
    const float tot = psum[b * 4 + 0] + psum[b * 4 + 1]
                    + psum[b * 4 + 2] + psum[b * 4 + 3];
    outb[b] = base[b] - (float)C * __logf(tot);
}

// ---------------------------------------------------------------------------
// K5 (unchanged, proven)
// ---------------------------------------------------------------------------
__global__ __launch_bounds__(256) void k5_final(
    const float* __restrict__ outb, float* __restrict__ out)
{
    __shared__ float red[4];
    const int tid = threadIdx.x;
    float s = outb[tid];
    s = wave_reduce(s);
    if ((tid & 63) == 0) red[tid >> 6] = s;
    __syncthreads();
    if (tid == 0) out[0] = red[0] + red[1] + red[2] + red[3];
}

extern "C" void kernel_launch(void* const* d_in, const int* in_sizes, int n_in,
                              void* d_out, int out_size, void* d_ws, size_t ws_size,
                              hipStream_t stream)
{
    const int*   center_id     = (const int*)d_in[0];
    const int*   context_ids   = (const int*)d_in[1];
    const float* embeddings    = (const float*)d_in[2];
    const float* prior_means_w = (const float*)d_in[3];
    const float* prior_vars_w  = (const float*)d_in[4];
    const float* enc_W         = (const float*)d_in[5];
    const float* enc_b         = (const float*)d_in[6];
    const float* mean_W        = (const float*)d_in[7];
    const float* mean_b        = (const float*)d_in[8];
    const float* var_W         = (const float*)d_in[9];
    const float* var_b         = (const float*)d_in[10];
    const float* vocab_W       = (const float*)d_in[11];
    const float* vocab_b       = (const float*)d_in[12];
    const float* epsilon       = (const float*)d_in[13];

    char* ws = (char*)d_ws;
    ushort_t* xbf     = (ushort_t*)ws;  ws += (size_t)MPAD * TWO_D * 2;   // 4 MB
    ushort_t* h_bf    = (ushort_t*)ws;  ws += (size_t)B * TWO_D * 2;      // 256 KB
    float*    mv      = (float*)ws;     ws += (size_t)B * TWO_D * 4;      // 512 KB
    ushort_t* zp      = (ushort_t*)ws;  ws += (size_t)B * D * 2;          // 128 KB
    float*    base    = (float*)ws;     ws += B * 4;
    float*    outb    = (float*)ws;     ws += B * 4;
    float*    psum    = (float*)ws;     ws += 1024 * 4;
    ushort_t* logits  = (ushort_t*)ws;                                    // 25.6 MB

    hipLaunchKernelGGL(k0_gather, dim3(2048), dim3(256), 0, stream,
                       center_id, context_ids, embeddings, xbf);
    hipLaunchKernelGGL(k_enc, dim3(512), dim3(256), 0, stream,
                       enc_W, enc_b, xbf, h_bf);
    hipLaunchKernelGGL(k_heads, dim3(32), dim3(256), 0, stream,
                       mean_W, mean_b, var_W, var_b, h_bf, mv);
    hipLaunchKernelGGL(k_z, dim3(B), dim3(256), 0, stream,
                       center_id, context_ids, prior_means_w, prior_vars_w,
                       vocab_W, vocab_b, epsilon, mv, zp, base);
    hipLaunchKernelGGL(k3a_gemm, dim3(NBLK), dim3(256), 0, stream,
                       vocab_W, zp, logits);
    hipLaunchKernelGGL(k3b_expsum, dim3(1024), dim3(256), 0, stream,
                       logits, vocab_b, psum);
    hipLaunchKernelGGL(k4_lse, dim3(1), dim3(256), 0, stream, psum, base, outb);
    hipLaunchKernelGGL(k5_final, dim3(1), dim3(256), 0, stream, outb, (float*)d_out);
}

// Round 14
// 67.796 us; speedup vs baseline: 2.6210x; 1.0428x over previous
//
#include <hip/hip_runtime.h>
#include <hip/hip_bf16.h>

// Sizes fixed by the reference
#define V 50000
#define D 256
#define B 256
#define C 10
#define TWO_D 512
#define VBLK 64
#define NBLK ((V + VBLK - 1) / VBLK)   // 782
#define VPAD (NBLK * VBLK)             // 50048
#define QV (VPAD / 4)                  // 12512
#define MPAD 4096                      // 256 b * 16 (c padded 10 -> 16)

typedef __bf16 bf16x8 __attribute__((ext_vector_type(8)));
typedef float f32x4 __attribute__((ext_vector_type(4)));
typedef unsigned short ushort_t;
typedef unsigned int uint_t;

__device__ inline ushort_t f2bf(float f) {
    uint_t u = __builtin_bit_cast(uint_t, f);
    uint_t r = (u + 0x7FFFu + ((u >> 16) & 1u)) >> 16;
    return (ushort_t)r;
}

__device__ inline float bf2f(ushort_t u) {
    return __builtin_bit_cast(float, (uint_t)u << 16);
}

__device__ inline float softplus_f(float x) {
    return (x > 0.f) ? (x + log1pf(__expf(-x))) : log1pf(__expf(x));
}

__device__ inline float wave_reduce(float v) {
    #pragma unroll
    for (int m = 1; m < 64; m <<= 1) v += __shfl_xor(v, m);
    return v;
}

// ---------------------------------------------------------------------------
// K0 (unchanged, proven)
// ---------------------------------------------------------------------------
__global__ __launch_bounds__(256) void k0_gather(
    const int* __restrict__ center_id, const int* __restrict__ context_ids,
    const float* __restrict__ embeddings, ushort_t* __restrict__ xbf)
{
    const int idx = blockIdx.x * 256 + threadIdx.x;
    const int m = idx >> 7;
    const int q = idx & 127;
    const int k = q * 4;
    const int b = m >> 4, c = m & 15;
    ushort4 o;
    if (k < D) {
        const float4 v = *(const float4*)(embeddings + center_id[b] * D + k);
        o.x = f2bf(v.x); o.y = f2bf(v.y); o.z = f2bf(v.z); o.w = f2bf(v.w);
    } else if (c < C) {
        const float4 v = *(const float4*)(embeddings + context_ids[b * C + c] * D + (k - D));
        o.x = f2bf(v.x); o.y = f2bf(v.y); o.z = f2bf(v.z); o.w = f2bf(v.w);
    } else {
        o.x = 0; o.y = 0; o.z = 0; o.w = 0;
    }
    *(ushort4*)(xbf + idx * 4) = o;
}

// ---------------------------------------------------------------------------
// K_enc (unchanged, proven)
// ---------------------------------------------------------------------------
__global__ __launch_bounds__(256) void k_enc(
    const float* __restrict__ enc_W, const float* __restrict__ enc_b,
    const ushort_t* __restrict__ xbf, ushort_t* __restrict__ h_bf)
{
    __shared__ __align__(16) ushort_t wt[2][64 * 40];
    const int tid = threadIdx.x;
    const int mblk = blockIdx.x & 63;
    const int nblk = blockIdx.x >> 6;
    const int n0 = nblk * 64;
    const int wid = tid >> 6, lane = tid & 63;
    const int l15 = lane & 15, g = lane >> 4;

    const int r0 = tid >> 3, kq = tid & 7, r1 = r0 + 32;
    const float* src0 = enc_W + (n0 + r0) * TWO_D + kq * 4;
    const float* src1 = enc_W + (n0 + r1) * TWO_D + kq * 4;
    const int dst0 = r0 * 40 + kq * 4;
    const int dst1 = r1 * 40 + kq * 4;

    {
        const float4 na = *(const float4*)(src0);
        const float4 nb = *(const float4*)(src1);
        ushort4 pa, pb;
        pa.x = f2bf(na.x); pa.y = f2bf(na.y); pa.z = f2bf(na.z); pa.w = f2bf(na.w);
        pb.x = f2bf(nb.x); pb.y = f2bf(nb.y); pb.z = f2bf(nb.z); pb.w = f2bf(nb.w);
        *(ushort4*)(&wt[0][dst0]) = pa;
        *(ushort4*)(&wt[0][dst1]) = pb;
    }
    __syncthreads();

    const int rowA = mblk * 64 + wid * 16 + l15;
    f32x4 acc[4] = {};
    #pragma unroll 1
    for (int kk = 0; kk < 16; ++kk) {
        const int cur = kk & 1, nxt = cur ^ 1;
        float4 na, nb;
        if (kk < 15) {
            na = *(const float4*)(src0 + (kk + 1) * 32);
            nb = *(const float4*)(src1 + (kk + 1) * 32);
        }
        const bf16x8 A = *(const bf16x8*)(xbf + rowA * TWO_D + kk * 32 + g * 8);
        bf16x8 Bf[4];
        #pragma unroll
        for (int vt = 0; vt < 4; ++vt)
            Bf[vt] = *(const bf16x8*)(&wt[cur][(vt * 16 + l15) * 40 + g * 8]);
        #pragma unroll
        for (int vt = 0; vt < 4; ++vt)
            acc[vt] = __builtin_amdgcn_mfma_f32_16x16x32_bf16(A, Bf[vt], acc[vt], 0, 0, 0);
        if (kk < 15) {
            ushort4 pa, pb;
            pa.x = f2bf(na.x); pa.y = f2bf(na.y); pa.z = f2bf(na.z); pa.w = f2bf(na.w);
            pb.x = f2bf(nb.x); pb.y = f2bf(nb.y); pb.z = f2bf(nb.z); pb.w = f2bf(nb.w);
            *(ushort4*)(&wt[nxt][dst0]) = pa;
            *(ushort4*)(&wt[nxt][dst1]) = pb;
        }
        __syncthreads();
    }

    const int b = mblk * 4 + wid;
    #pragma unroll
    for (int vt = 0; vt < 4; ++vt) {
        const int j = n0 + vt * 16 + l15;
        const float bias = enc_b[j];
        float s = 0.f;
        #pragma unroll
        for (int r = 0; r < 4; ++r) {
            const int c = g * 4 + r;
            const float vv = acc[vt][r] + bias;
            s += (c < C) ? fmaxf(vv, 0.f) : 0.f;
        }
        s += __shfl_xor(s, 16);
        s += __shfl_xor(s, 32);
        if (g == 0) h_bf[b * TWO_D + j] = f2bf(s);
    }
}

// ---------------------------------------------------------------------------
// K_heads (unchanged, proven)
// ---------------------------------------------------------------------------
__global__ __launch_bounds__(256) void k_heads(
    const float* __restrict__ mean_W, const float* __restrict__ mean_b,
    const float* __restrict__ var_W, const float* __restrict__ var_b,
    const ushort_t* __restrict__ h_bf, float* __restrict__ mv)
{
    __shared__ __align__(16) ushort_t wt[2][64 * 40];
    const int tid = threadIdx.x;
    const int mblk = blockIdx.x & 3;
    const int nblk = blockIdx.x >> 2;
    const int n0 = nblk * 64;
    const float* Wsrc = (nblk < 4) ? mean_W : var_W;
    const float* bsrc = (nblk < 4) ? mean_b : var_b;
    const int nloc = (nblk & 3) * 64;
    const int wid = tid >> 6, lane = tid & 63;
    const int l15 = lane & 15, g = lane >> 4;

    const int r0 = tid >> 3, kq = tid & 7, r1 = r0 + 32;
    const float* src0 = Wsrc + (nloc + r0) * TWO_D + kq * 4;
    const float* src1 = Wsrc + (nloc + r1) * TWO_D + kq * 4;
    const int dst0 = r0 * 40 + kq * 4;
    const int dst1 = r1 * 40 + kq * 4;

    {
        const float4 na = *(const float4*)(src0);
        const float4 nb = *(const float4*)(src1);
        ushort4 pa, pb;
        pa.x = f2bf(na.x); pa.y = f2bf(na.y); pa.z = f2bf(na.z); pa.w = f2bf(na.w);
        pb.x = f2bf(nb.x); pb.y = f2bf(nb.y); pb.z = f2bf(nb.z); pb.w = f2bf(nb.w);
        *(ushort4*)(&wt[0][dst0]) = pa;
        *(ushort4*)(&wt[0][dst1]) = pb;
    }
    __syncthreads();

    const int rowA = mblk * 64 + wid * 16 + l15;
    f32x4 acc[4] = {};
    #pragma unroll 1
    for (int kk = 0; kk < 16; ++kk) {
        const int cur = kk & 1, nxt = cur ^ 1;
        float4 na, nb;
        if (kk < 15) {
            na = *(const float4*)(src0 + (kk + 1) * 32);
            nb = *(const float4*)(src1 + (kk + 1) * 32);
        }
        const bf16x8 A = *(const bf16x8*)(h_bf + rowA * TWO_D + kk * 32 + g * 8);
        bf16x8 Bf[4];
        #pragma unroll
        for (int vt = 0; vt < 4; ++vt)
            Bf[vt] = *(const bf16x8*)(&wt[cur][(vt * 16 + l15) * 40 + g * 8]);
        #pragma unroll
        for (int vt = 0; vt < 4; ++vt)
            acc[vt] = __builtin_amdgcn_mfma_f32_16x16x32_bf16(A, Bf[vt], acc[vt], 0, 0, 0);
        if (kk < 15) {
            ushort4 pa, pb;
            pa.x = f2bf(na.x); pa.y = f2bf(na.y); pa.z = f2bf(na.z); pa.w = f2bf(na.w);
            pb.x = f2bf(nb.x); pb.y = f2bf(nb.y); pb.z = f2bf(nb.z); pb.w = f2bf(nb.w);
            *(ushort4*)(&wt[nxt][dst0]) = pa;
            *(ushort4*)(&wt[nxt][dst1]) = pb;
        }
        __syncthreads();
    }

    const int rowBase = mblk * 64 + wid * 16;
    #pragma unroll
    for (int vt = 0; vt < 4; ++vt) {
        const int col = n0 + vt * 16 + l15;
        const float bias = bsrc[nloc + vt * 16 + l15];
        #pragma unroll
        for (int r = 0; r < 4; ++r) {
            const int row = rowBase + g * 4 + r;
            mv[row * TWO_D + col] = acc[vt][r] + bias;
        }
    }
}

// ---------------------------------------------------------------------------
// K_z (unchanged — packed zp write, proven)
// ---------------------------------------------------------------------------
__global__ __launch_bounds__(256) void k_z(
    const int* __restrict__ center_id, const int* __restrict__ context_ids,
    const float* __restrict__ prior_means_w, const float* __restrict__ prior_vars_w,
    const float* __restrict__ vocab_W, const float* __restrict__ vocab_b,
    const float* __restrict__ epsilon, const float* __restrict__ mv,
    ushort_t* __restrict__ zp, float* __restrict__ base)
{
    __shared__ float red[8];
    __shared__ int cids[C];
    const int b = blockIdx.x, tid = threadIdx.x;
    const int cid = center_id[b];
    if (tid < C) cids[tid] = context_ids[b * C + tid];
    __syncthreads();

    const int i = tid;
    const float mean = mv[b * TWO_D + i];
    const float a    = mv[b * TWO_D + D + i];
    const float var  = softplus_f(a);
    const float z    = mean + __expf(0.5f * var) * epsilon[i];

    {
        const int mt  = b >> 4;
        const int kkz = i >> 5;
        const int lz  = ((i >> 3) & 3) * 16 + (b & 15);
        zp[(mt * 8 + kkz) * 512 + lz * 8 + (i & 7)] = f2bf(z);
    }

    const float pm = prior_means_w[cid * D + i];
    const float pv = softplus_f(prior_vars_w[cid * D + i]);
    const float dm = pm - mean;
    float klt = var / pv + dm * dm / pv - 1.f + __logf(pv) - __logf(var);

    float wsum = 0.f;
    #pragma unroll
    for (int c = 0; c < C; ++c) wsum += vocab_W[cids[c] * D + i];
    float p = z * wsum;

    klt = wave_reduce(klt);
    p = wave_reduce(p);
    const int wid = tid >> 6, lane = tid & 63;
    if (lane == 0) { red[wid] = klt; red[4 + wid] = p; }
    __syncthreads();
    if (tid == 0) {
        const float kl = 0.5f * (red[0] + red[1] + red[2] + red[3]);
        float cs = red[4] + red[5] + red[6] + red[7];
        #pragma unroll
        for (int c = 0; c < C; ++c) cs += vocab_b[cids[c]];
        base[b] = cs - kl;
    }
}

// ---------------------------------------------------------------------------
// K3a: PURE GEMM with FORCED in-flight staging.
// The 16 staging loads are inline-asm global_load_dwordx4 with "=v" outputs:
// the compiler MUST allocate 16 live f32x4s and issue all 16 before the
// single vmcnt(0) — it cannot register-miser the burst down to depth ~5
// (round-4/12 failure mode, VGPR_Count 40/56). launch_bounds (256,3) gives
// the VGPR headroom (grid 782 = 3 blocks/CU anyway).
// Epilogue: bias folded into logits (saves k3b's 51 MB bias re-read).
// ---------------------------------------------------------------------------
__global__ __launch_bounds__(256, 3) void k3a_gemm(
    const float* __restrict__ vocab_W, const float* __restrict__ vocab_b,
    const ushort_t* __restrict__ zp, ushort_t* __restrict__ logits)
{
    __shared__ __align__(16) ushort_t ldsB[64 * 256];   // 32 KB

    const int tid = threadIdx.x;
    const int blk = blockIdx.x;              // 0..781
    const int v0 = blk * VBLK;
    const int wid = tid >> 6, lane = tid & 63;
    const int l15 = lane & 15, g = lane >> 4;

    float bias[4];
    #pragma unroll
    for (int vt = 0; vt < 4; ++vt)
        bias[vt] = vocab_b[min(v0 + vt * 16 + l15, V - 1)];

    // ---- stage: 16 coalesced 1KB-row loads, forced in flight via asm
    f32x4 st[16];
    const int maxidx = V * D - 4;
    #pragma unroll
    for (int j = 0; j < 16; ++j) {
        const int idx = min(v0 * D + j * 4096 + tid * 4, maxidx);
        const float* p = vocab_W + idx;
        asm volatile("global_load_dwordx4 %0, %1, off"
                     : "=v"(st[j]) : "v"(p) : "memory");
    }
    asm volatile("s_waitcnt vmcnt(0)" ::: "memory");
    __builtin_amdgcn_sched_barrier(0);

    #pragma unroll
    for (int j = 0; j < 16; ++j) {
        const int row = j * 4 + wid;                      // wave-uniform
        ushort4 p;
        p.x = f2bf(st[j][0]); p.y = f2bf(st[j][1]);
        p.z = f2bf(st[j][2]); p.w = f2bf(st[j][3]);
        *(ushort4*)(ldsB + row * 256 + ((lane * 4) ^ ((row & 7) << 3))) = p;
    }
    __syncthreads();

    // ---- MFMA: 8 k-steps, no barriers. A from packed zp (L2-hot).
    f32x4 acc[4][4] = {};
    #pragma unroll 1
    for (int kk = 0; kk < 8; ++kk) {
        bf16x8 A[4], Bf[4];
        #pragma unroll
        for (int bt = 0; bt < 4; ++bt) {
            const int mt = wid * 4 + bt;
            A[bt] = *(const bf16x8*)(zp + ((mt * 8 + kk) << 9) + (lane << 3));
        }
        #pragma unroll
        for (int vt = 0; vt < 4; ++vt) {
            const int row = vt * 16 + l15;
            Bf[vt] = *(const bf16x8*)(
                ldsB + row * 256 + ((kk * 32 + g * 8) ^ ((row & 7) << 3)));
        }
        #pragma unroll
        for (int bt = 0; bt < 4; ++bt)
            #pragma unroll
            for (int vt = 0; vt < 4; ++vt)
                acc[bt][vt] = __builtin_amdgcn_mfma_f32_16x16x32_bf16(
                    A[bt], Bf[vt], acc[bt][vt], 0, 0, 0);
    }

    // ---- epilogue: bf16 stores of (logit + bias)
    #pragma unroll
    for (int bt = 0; bt < 4; ++bt)
        #pragma unroll
        for (int r = 0; r < 4; ++r) {
            const int brow = wid * 64 + bt * 16 + g * 4 + r;
            #pragma unroll
            for (int vt = 0; vt < 4; ++vt)
                logits[brow * VPAD + v0 + vt * 16 + l15] =
                    f2bf(acc[bt][vt][r] + bias[vt]);
        }
}

// ---------------------------------------------------------------------------
// K3b: PURE STREAM-REDUCE. 1024 blocks x 256 thr; block (b, q) sums
// exp(logits) (bias pre-folded) over v in [q*QV,(q+1)*QV). Coalesced ushort4.
// ---------------------------------------------------------------------------
__global__ __launch_bounds__(256) void k3b_expsum(
    const ushort_t* __restrict__ logits, float* __restrict__ psum)
{
    __shared__ float red[4];
    const int b = blockIdx.x >> 2, q = blockIdx.x & 3;
    const int tid = threadIdx.x;
    const int vbase = q * QV;
    const ushort_t* src = logits + b * VPAD + vbase;
    float s = 0.f;
    for (int i = tid * 8; i < QV; i += 2048) {
        const ushort4 u0 = *(const ushort4*)(src + i);
        const ushort4 u1 = *(const ushort4*)(src + i + 4);
        const int v = vbase + i;
        if (v + 8 <= V) {
            s += __expf(bf2f(u0.x)) + __expf(bf2f(u0.y))
               + __expf(bf2f(u0.z)) + __expf(bf2f(u0.w))
               + __expf(bf2f(u1.x)) + __expf(bf2f(u1.y))
               + __expf(bf2f(u1.z)) + __expf(bf2f(u1.w));
        } else {
            const ushort_t us[8] = {u0.x, u0.y, u0.z, u0.w, u1.x, u1.y, u1.z, u1.w};
            #pragma unroll
            for (int j = 0; j < 8; ++j)
                if (v + j < V) s += __expf(bf2f(us[j]));
        }
    }
    s = wave_reduce(s);
    if ((tid & 63) == 0) red[tid >> 6] = s;
    __syncthreads();
    if (tid == 0) psum[blockIdx.x] = red[0] + red[1] + red[2] + red[3];
}

// ---------------------------------------------------------------------------
// K4: tiny — one block; per-b total = 4 quarter-sums; LSE.
// ---------------------------------------------------------------------------
__global__ __launch_bounds__(256) void k4_lse(
    const float* __restrict__ psum, const float* __restrict__ base,
    float* __restrict__ outb)
{
    const int b = threadIdx.x;
    const float tot = psum[b * 4 + 0] + psum[b * 4 + 1]
                    + psum[b * 4 + 2] + psum[b * 4 + 3];
    outb[b] = base[b] - (float)C * __logf(tot);
}

// ---------------------------------------------------------------------------
// K5 (unchanged, proven)
// ---------------------------------------------------------------------------
__global__ __launch_bounds__(256) void k5_final(
    const float* __restrict__ outb, float* __restrict__ out)
{
    __shared__ float red[4];
    const int tid = threadIdx.x;
    float s = outb[tid];
    s = wave_reduce(s);
    if ((tid & 63) == 0) red[tid >> 6] = s;
    __syncthreads();
    if (tid == 0) out[0] = red[0] + red[1] + red[2] + red[3];
}

extern "C" void kernel_launch(void* const* d_in, const int* in_sizes, int n_in,
                              void* d_out, int out_size, void* d_ws, size_t ws_size,
                              hipStream_t stream)
{
    const int*   center_id     = (const int*)d_in[0];
    const int*   context_ids   = (const int*)d_in[1];
    const float* embeddings    = (const float*)d_in[2];
    const float* prior_means_w = (const float*)d_in[3];
    const float* prior_vars_w  = (const float*)d_in[4];
    const float* enc_W         = (const float*)d_in[5];
    const float* enc_b         = (const float*)d_in[6];
    const float* mean_W        = (const float*)d_in[7];
    const float* mean_b        = (const float*)d_in[8];
    const float* var_W         = (const float*)d_in[9];
    const float* var_b         = (const float*)d_in[10];
    const float* vocab_W       = (const float*)d_in[11];
    const float* vocab_b       = (const float*)d_in[12];
    const float* epsilon       = (const float*)d_in[13];

    char* ws = (char*)d_ws;
    ushort_t* xbf     = (ushort_t*)ws;  ws += (size_t)MPAD * TWO_D * 2;   // 4 MB
    ushort_t* h_bf    = (ushort_t*)ws;  ws += (size_t)B * TWO_D * 2;      // 256 KB
    float*    mv      = (float*)ws;     ws += (size_t)B * TWO_D * 4;      // 512 KB
    ushort_t* zp      = (ushort_t*)ws;  ws += (size_t)B * D * 2;          // 128 KB
    float*    base    = (float*)ws;     ws += B * 4;
    float*    outb    = (float*)ws;     ws += B * 4;
    float*    psum    = (float*)ws;     ws += 1024 * 4;
    ushort_t* logits  = (ushort_t*)ws;                                    // 25.6 MB

    hipLaunchKernelGGL(k0_gather, dim3(2048), dim3(256), 0, stream,
                       center_id, context_ids, embeddings, xbf);
    hipLaunchKernelGGL(k_enc, dim3(512), dim3(256), 0, stream,
                       enc_W, enc_b, xbf, h_bf);
    hipLaunchKernelGGL(k_heads, dim3(32), dim3(256), 0, stream,
                       mean_W, mean_b, var_W, var_b, h_bf, mv);
    hipLaunchKernelGGL(k_z, dim3(B), dim3(256), 0, stream,
                       center_id, context_ids, prior_means_w, prior_vars_w,
                       vocab_W, vocab_b, epsilon, mv, zp, base);
    hipLaunchKernelGGL(k3a_gemm, dim3(NBLK), dim3(256), 0, stream,
                       vocab_W, vocab_b, zp, logits);
    hipLaunchKernelGGL(k3b_expsum, dim3(1024), dim3(256), 0, stream,
                       logits, psum);
    hipLaunchKernelGGL(k4_lse, dim3(1), dim3(256), 0, stream, psum, base, outb);
    hipLaunchKernelGGL(k5_final, dim3(1), dim3(256), 0, stream, outb, (float*)d_out);
}